// Round 4
// baseline (920.703 us; speedup 1.0000x reference)
//
#include <hip/hip_runtime.h>
#include <hip/hip_bf16.h>
#include <math.h>

#define HD 128
#define NPB 512        // nodes per bucket
#define CAP 16384      // edge capacity per bucket (avg ~8163 -> 2x headroom)
#define SCHUNK 4096    // edges per scatter block

typedef __attribute__((ext_vector_type(8))) short  bf16x8;
typedef __attribute__((ext_vector_type(4))) float  f32x4;

__device__ __forceinline__ float lrelu(float v) { return v > 0.0f ? v : 0.1f * v; }

__device__ __forceinline__ unsigned short f2bf(float f) {
  union { float f; unsigned u; } c; c.f = f;
  unsigned u = c.u + 0x7fffu + ((c.u >> 16) & 1u);   // RNE
  return (unsigned short)(u >> 16);
}
__device__ __forceinline__ float bf2f(unsigned short u) {
  return __uint_as_float((unsigned)u << 16);
}

// slab layout: act[s][node][16] for s=0..7; element (node, col) at
// slab(col>>4) * N16 + node*16 + (col&15), N16 = N*16.

// ---------------- embedding layer 1 (all types, padded node ids) ----------------
__global__ __launch_bounds__(256)
void embed1_kernel(const float* __restrict__ xg, const float* __restrict__ xl,
                   const float* __restrict__ xo, const float* __restrict__ xe,
                   const float* __restrict__ Wg, const float* __restrict__ bg,
                   const float* __restrict__ Wl, const float* __restrict__ bl,
                   const float* __restrict__ Wo, const float* __restrict__ bo,
                   const float* __restrict__ We, const float* __restrict__ be,
                   unsigned short* __restrict__ h1, int4 padCum, int4 realCnt) {
  int p = blockIdx.x * 2 + (threadIdx.x >> 7);
  if (p >= padCum.w) return;
  int j = threadIdx.x & 127;
  int typ = (p < padCum.x) ? 0 : (p < padCum.y) ? 1 : (p < padCum.z) ? 2 : 3;
  int padStart = (typ == 0) ? 0 : (typ == 1) ? padCum.x : (typ == 2) ? padCum.y : padCum.z;
  int cnt = (typ == 0) ? realCnt.x : (typ == 1) ? realCnt.y : (typ == 2) ? realCnt.z : realCnt.w;
  int loc = p - padStart;
  if (loc >= cnt) return;
  const float *x, *W, *bb; int IN;
  if (typ == 0)      { x = xg; W = Wg; bb = bg; IN = 3; }
  else if (typ == 1) { x = xl; W = Wl; bb = bl; IN = 3; }
  else if (typ == 2) { x = xo; W = Wo; bb = bo; IN = 6; }
  else               { x = xe; W = We; bb = be; IN = 6; }
  float acc = bb[j];
  for (int k = 0; k < IN; k++) acc += x[(size_t)loc * IN + k] * W[k * HD + j];
  h1[(size_t)p * HD + j] = f2bf(lrelu(acc));
}

// ---------------- weight repack + invptv + gcnt zero ----------------
__global__ __launch_bounds__(256)
void wprep_all_kernel(const float* __restrict__ Wg2, const float* __restrict__ Wld2,
                      const float* __restrict__ Wor2, const float* __restrict__ Wex2,
                      const float* __restrict__ Wl_h, const float* __restrict__ Wr_h,
                      unsigned short* __restrict__ Wp,
                      const int* __restrict__ ptv, int* __restrict__ inv,
                      int* __restrict__ gcnt, int n) {
  int tid = blockIdx.x * 256 + threadIdx.x;      // 10 * 16384 total
  if (tid < 256) gcnt[tid] = 0;
  if (tid < n) inv[ptv[tid]] = tid;
  int m = tid >> 14;
  int i = tid & 16383;
  const float* src; unsigned short* dst;
  switch (m) {
    case 0: src = Wg2;  dst = Wp;             break;
    case 1: src = Wld2; dst = Wp + 16384;     break;
    case 2: src = Wor2; dst = Wp + 2 * 16384; break;
    case 3: src = Wex2; dst = Wp + 3 * 16384; break;
    default: {
      int mm = m - 4; int l = mm >> 1; int isR = mm & 1;
      src = (isR ? Wr_h : Wl_h) + (size_t)l * 16384;
      dst = Wp + 4 * 16384 + (size_t)l * 32768 + (isR ? 16384 : 0);
    }
  }
  int k = i >> 7, j = i & 127;
  int ks = k >> 5, g = (k >> 3) & 3, b = k & 7;
  dst[((ks * 128 + j) * 4 + g) * 8 + b] = f2bf(src[i]);
}

// ---------------- embedding layer 2 (MFMA), h1 row-major -> slab out ----------------
__global__ __launch_bounds__(256)
void mfma_embed2_kernel(const unsigned short* __restrict__ h1,
                        const unsigned short* __restrict__ Wp,
                        const float* __restrict__ b_g, const float* __restrict__ b_ld,
                        const float* __restrict__ b_or, const float* __restrict__ b_ex,
                        const int* __restrict__ inv, unsigned short* __restrict__ out,
                        int4 padCum, int4 realStart, int4 realCnt, int N16) {
  const int t = threadIdx.x, w = t >> 6, l = t & 63;
  const int lr = l & 15, lg = l >> 4;
  const int prow0 = blockIdx.x * 64 + w * 16;
  int typ = (prow0 < padCum.x) ? 0 : (prow0 < padCum.y) ? 1 : (prow0 < padCum.z) ? 2 : 3;
  int padStart = (typ == 0) ? 0 : (typ == 1) ? padCum.x : (typ == 2) ? padCum.y : padCum.z;
  int rStart = (typ == 0) ? realStart.x : (typ == 1) ? realStart.y : (typ == 2) ? realStart.z : realStart.w;
  int cnt = (typ == 0) ? realCnt.x : (typ == 1) ? realCnt.y : (typ == 2) ? realCnt.z : realCnt.w;
  const float* bias = (typ == 0) ? b_g : (typ == 1) ? b_ld : (typ == 2) ? b_or : b_ex;

  int raLoc = prow0 + lr - padStart; if (raLoc >= cnt) raLoc = cnt - 1;
  const unsigned short* abase = h1 + (size_t)(padStart + raLoc) * HD + 8 * lg;
  const unsigned short* wbase = Wp + (size_t)typ * 16384 + lr * 32 + lg * 8;

  f32x4 acc[8];
  #pragma unroll
  for (int cb = 0; cb < 8; cb++) {
    float bv = bias[cb * 16 + lr];
    acc[cb] = (f32x4){bv, bv, bv, bv};
  }
  #pragma unroll
  for (int ks = 0; ks < 4; ks++) {
    bf16x8 af = *(const bf16x8*)(abase + ks * 32);
    #pragma unroll
    for (int cb = 0; cb < 8; cb++) {
      bf16x8 bfv = *(const bf16x8*)(wbase + (size_t)(ks * 128 + cb * 16) * 32);
      acc[cb] = __builtin_amdgcn_mfma_f32_16x16x32_bf16(af, bfv, acc[cb], 0, 0, 0);
    }
  }
  int tgt[4];
  #pragma unroll
  for (int r = 0; r < 4; r++) {
    int locRow = prow0 + lg * 4 + r - padStart;
    tgt[r] = (locRow < cnt) ? inv[rStart + locRow] : -1;
  }
  #pragma unroll
  for (int cb = 0; cb < 8; cb++) {
    #pragma unroll
    for (int r = 0; r < 4; r++) {
      if (tgt[r] >= 0)
        out[(size_t)cb * N16 + (size_t)tgt[r] * 16 + lr] = f2bf(lrelu(acc[cb][r]));
    }
  }
}

// ---------------- MFMA combine (slab in, slab out / z out) ----------------
// EMIT_Z: instead of writing x3 slabs, compute zl = x3.wl, zr = x3.wr
template<bool EMIT_Z>
__global__ __launch_bounds__(256)
void mfma_comb_kernel(const unsigned short* __restrict__ Aa, const unsigned short* __restrict__ Ab,
                      const unsigned short* __restrict__ Wp, const float* __restrict__ bias,
                      unsigned short* __restrict__ out,
                      const float* __restrict__ wl, const float* __restrict__ wr,
                      float* __restrict__ zl, float* __restrict__ zr,
                      int n_rows, int N16) {
  const int t = threadIdx.x;
  const int w = t >> 6;
  const int l = t & 63;
  const int lr = l & 15;
  const int lg = l >> 4;
  const int row0 = blockIdx.x * 64 + w * 16;
  int ra = row0 + lr; if (ra >= n_rows) ra = n_rows - 1;

  const unsigned short* wbase = Wp + (size_t)lr * 32 + (size_t)lg * 8;
  // slab A-read base: slab index 2*ks + (lg>>1), in-slab offset (lg&1)*8
  const unsigned short* abase = Aa + (size_t)(lg >> 1) * N16 + (size_t)ra * 16 + (lg & 1) * 8;
  const unsigned short* bbase = Ab + (size_t)(lg >> 1) * N16 + (size_t)ra * 16 + (lg & 1) * 8;

  f32x4 acc[8];
  #pragma unroll
  for (int cb = 0; cb < 8; cb++) {
    float bv = bias[cb * 16 + lr];
    acc[cb] = (f32x4){bv, bv, bv, bv};
  }
  #pragma unroll
  for (int ks = 0; ks < 4; ks++) {
    bf16x8 af = *(const bf16x8*)(abase + (size_t)(2 * ks) * N16);
    #pragma unroll
    for (int cb = 0; cb < 8; cb++) {
      bf16x8 bfv = *(const bf16x8*)(wbase + (size_t)(ks * 128 + cb * 16) * 32);
      acc[cb] = __builtin_amdgcn_mfma_f32_16x16x32_bf16(af, bfv, acc[cb], 0, 0, 0);
    }
  }
  #pragma unroll
  for (int ks = 0; ks < 4; ks++) {
    bf16x8 af = *(const bf16x8*)(bbase + (size_t)(2 * ks) * N16);
    #pragma unroll
    for (int cb = 0; cb < 8; cb++) {
      bf16x8 bfv = *(const bf16x8*)(wbase + (size_t)((4 + ks) * 128 + cb * 16) * 32);
      acc[cb] = __builtin_amdgcn_mfma_f32_16x16x32_bf16(af, bfv, acc[cb], 0, 0, 0);
    }
  }

  if constexpr (!EMIT_Z) {
    #pragma unroll
    for (int cb = 0; cb < 8; cb++) {
      #pragma unroll
      for (int r = 0; r < 4; r++) {
        int node = row0 + lg * 4 + r;
        if (node < n_rows)
          out[(size_t)cb * N16 + (size_t)node * 16 + lr] = f2bf(lrelu(acc[cb][r]));
      }
    }
  } else {
    float vl[4] = {0.f, 0.f, 0.f, 0.f}, vr[4] = {0.f, 0.f, 0.f, 0.f};
    #pragma unroll
    for (int cb = 0; cb < 8; cb++) {
      float wlv = wl[cb * 16 + lr];
      float wrv = wr[cb * 16 + lr];
      #pragma unroll
      for (int r = 0; r < 4; r++) {
        float x3 = lrelu(acc[cb][r]);
        vl[r] += x3 * wlv;
        vr[r] += x3 * wrv;
      }
    }
    #pragma unroll
    for (int r = 0; r < 4; r++) {
      #pragma unroll
      for (int d = 1; d < 16; d <<= 1) {
        vl[r] += __shfl_xor(vl[r], d, 64);
        vr[r] += __shfl_xor(vr[r], d, 64);
      }
    }
    if (lr == 0) {
      #pragma unroll
      for (int r = 0; r < 4; r++) {
        int node = row0 + lg * 4 + r;
        if (node < n_rows) { zl[node] = vl[r]; zr[node] = vr[r]; }
      }
    }
  }
}

// ---------------- CSR build phase 1: bucket scatter (packed int) ----------------
__global__ __launch_bounds__(256)
void bucket_scatter_kernel(const int* __restrict__ esrc, const int* __restrict__ edst,
                           int* __restrict__ gcnt, int* __restrict__ ebuf, int nE) {
  __shared__ int cnt[256];
  __shared__ int cur[256];
  const int t = threadIdx.x;
  const int c0 = blockIdx.x * SCHUNK;
  int s_arr[16], d_arr[16];
  cnt[t] = 0;
  __syncthreads();
  #pragma unroll
  for (int k = 0; k < 16; k++) {
    int idx = c0 + k * 256 + t;
    if (idx < nE) {
      s_arr[k] = esrc[idx];
      int d = edst[idx];
      d_arr[k] = d;
      atomicAdd(&cnt[d >> 9], 1);
    } else d_arr[k] = -1;
  }
  __syncthreads();
  if (cnt[t] > 0) cur[t] = atomicAdd(&gcnt[t], cnt[t]);
  __syncthreads();
  #pragma unroll
  for (int k = 0; k < 16; k++) {
    if (d_arr[k] >= 0) {
      int b = d_arr[k] >> 9;
      int p = atomicAdd(&cur[b], 1);
      ebuf[(size_t)b * CAP + p] = (s_arr[k] << 9) | (d_arr[k] & 511);
    }
  }
}

__device__ __forceinline__ int wave_incl_scan(int v) {
  int lane = threadIdx.x & 63;
  #pragma unroll
  for (int d = 1; d < 64; d <<= 1) {
    int tv = __shfl_up(v, d, 64);
    if (lane >= d) v += tv;
  }
  return v;
}

// ---------------- CSR build phase 2: per-bucket local build ----------------
__global__ __launch_bounds__(256)
void bucket_build_kernel(const int* __restrict__ ebuf, const int* __restrict__ gcnt,
                         int* __restrict__ csr, int* __restrict__ offs,
                         int* __restrict__ deg, float* __restrict__ inv_deg, int n) {
  __shared__ int hist[512];
  __shared__ int offl[512];
  __shared__ int wsum[4];
  const int b = blockIdx.x, t = threadIdx.x;
  const int cnt = gcnt[b];
  const size_t ebase = (size_t)b * CAP;
  hist[t] = 0; hist[t + 256] = 0;
  __syncthreads();
  for (int i = t; i < cnt; i += 256) {
    int e = ebuf[ebase + i];
    atomicAdd(&hist[e & 511], 1);
  }
  __syncthreads();
  int a0 = hist[2 * t], a1 = hist[2 * t + 1];
  int s = a0 + a1;
  int incl = wave_incl_scan(s);
  int wid = t >> 6;
  if ((t & 63) == 63) wsum[wid] = incl;
  __syncthreads();
  int wbase = 0;
  for (int w_ = 0; w_ < wid; w_++) wbase += wsum[w_];
  int excl = wbase + incl - s;
  offl[2 * t] = excl;
  offl[2 * t + 1] = excl + a0;
  __syncthreads();
  const int d0 = b << 9;
  for (int i = t; i < 512; i += 256) {
    int g = d0 + i;
    if (g < n) {
      offs[g] = b * CAP + offl[i];
      int dg = hist[i];
      deg[g] = dg;
      inv_deg[g] = 1.0f / fmaxf((float)dg, 1.0f);
    }
  }
  __syncthreads();
  for (int i = t; i < cnt; i += 256) {
    int e = ebuf[ebase + i];
    int p = atomicAdd(&offl[e & 511], 1);
    csr[ebase + p] = ((unsigned)e) >> 9;
  }
}

// ---------------- mean aggregation: slab-sliced, XCD-affine ----------------
// blockIdx.x = chunk*8 + slice; slice lands on XCD (slice) under round-robin
// dispatch, so each XCD's gathers hit only its own 3.2MB slab -> L2-resident.
__global__ __launch_bounds__(256)
void agg_slab_kernel(const unsigned short* __restrict__ x, const int* __restrict__ csr,
                     const int* __restrict__ offs, const int* __restrict__ deg,
                     const float* __restrict__ inv_deg, unsigned short* __restrict__ agg,
                     int n, int N16) {
  const int slice = blockIdx.x & 7;
  const int chunk = blockIdx.x >> 3;
  const int w = threadIdx.x >> 6, l = threadIdx.x & 63;
  const int e = l >> 3, c = l & 7;
  const unsigned short* xs = x + (size_t)slice * N16;
  unsigned short* as_ = agg + (size_t)slice * N16;
  const int node0 = chunk * 64 + w * 16;
  for (int ni = 0; ni < 16; ni++) {
    int node = node0 + ni;
    if (node >= n) break;
    int s0 = offs[node], d = deg[node];
    float a0 = 0.f, a1 = 0.f;
    for (int i = e; i < d; i += 8) {
      int src = csr[s0 + i];
      unsigned v = *(const unsigned*)(xs + (size_t)src * 16 + 2 * c);
      a0 += bf2f((unsigned short)(v & 0xffffu));
      a1 += bf2f((unsigned short)(v >> 16));
    }
    a0 += __shfl_xor(a0, 8, 64);  a1 += __shfl_xor(a1, 8, 64);
    a0 += __shfl_xor(a0, 16, 64); a1 += __shfl_xor(a1, 16, 64);
    a0 += __shfl_xor(a0, 32, 64); a1 += __shfl_xor(a1, 32, 64);
    if (e == 0) {
      float id = inv_deg[node];
      unsigned o = ((unsigned)f2bf(a1 * id) << 16) | (unsigned)f2bf(a0 * id);
      *(unsigned*)(as_ + (size_t)node * 16 + 2 * c) = o;
    }
  }
}

// ---------------- final: out = sigmoid(mean(zl) + zr + bl) ----------------
__global__ __launch_bounds__(256)
void zfinal_kernel(const float* __restrict__ zl, const float* __restrict__ zr,
                   const int* __restrict__ csr, const int* __restrict__ offs,
                   const int* __restrict__ deg, const float* __restrict__ inv_deg,
                   const float* __restrict__ bl, float* __restrict__ out, int n) {
  int i = blockIdx.x * 256 + threadIdx.x;
  if (i >= n) return;
  int s0 = offs[i], d = deg[i];
  float a = 0.f;
  #pragma unroll 4
  for (int e = 0; e < d; e++) a += zl[csr[s0 + e]];
  float s = a * inv_deg[i] + bl[0] + zr[i];
  out[i] = 1.0f / (1.0f + expf(-s));
}

extern "C" void kernel_launch(void* const* d_in, const int* in_sizes, int n_in,
                              void* d_out, int out_size, void* d_ws, size_t ws_size,
                              hipStream_t stream) {
  const float* x_gen  = (const float*)d_in[0];
  const float* x_load = (const float*)d_in[1];
  const float* x_or   = (const float*)d_in[2];
  const float* x_ex   = (const float*)d_in[3];
  const int*   edge   = (const int*)d_in[4];
  const int*   ptv    = (const int*)d_in[5];
  const float* Wg1  = (const float*)d_in[6],  *bg1  = (const float*)d_in[7];
  const float* Wg2  = (const float*)d_in[8],  *bg2  = (const float*)d_in[9];
  const float* Wld1 = (const float*)d_in[10], *bld1 = (const float*)d_in[11];
  const float* Wld2 = (const float*)d_in[12], *bld2 = (const float*)d_in[13];
  const float* Wor1 = (const float*)d_in[14], *bor1 = (const float*)d_in[15];
  const float* Wor2 = (const float*)d_in[16], *bor2 = (const float*)d_in[17];
  const float* Wex1 = (const float*)d_in[18], *bex1 = (const float*)d_in[19];
  const float* Wex2 = (const float*)d_in[20], *bex2 = (const float*)d_in[21];
  const float* Wl_h = (const float*)d_in[22], *bl_h = (const float*)d_in[23];
  const float* Wr_h = (const float*)d_in[24];
  const float* Wl_o = (const float*)d_in[25], *bl_o = (const float*)d_in[26];
  const float* Wr_o = (const float*)d_in[27];

  const int n_gen  = in_sizes[0] / 3;
  const int n_load = in_sizes[1] / 3;
  const int n_or   = in_sizes[2] / 6;
  const int n_ex   = in_sizes[3] / 6;
  const int nE     = in_sizes[4] / 2;
  const int N      = in_sizes[5];
  const int* esrc = edge;
  const int* edst = edge + nE;

  // padded segment geometry (each segment rounded to 64 rows)
  const int np0 = ((n_gen  + 63) / 64) * 64;
  const int np1 = ((n_load + 63) / 64) * 64;
  const int np2 = ((n_or   + 63) / 64) * 64;
  const int np3 = ((n_ex   + 63) / 64) * 64;
  const int NP  = np0 + np1 + np2 + np3;
  const int4 padCum    = make_int4(np0, np0 + np1, np0 + np1 + np2, NP);
  const int4 realStart = make_int4(0, n_gen, n_gen + n_load, n_gen + n_load + n_or);
  const int4 realCnt   = make_int4(n_gen, n_load, n_or, n_ex);
  const int N16 = N * 16;

  const int NB = (N + NPB - 1) / NPB;   // buckets (<=256 for N<=131072)

  // ---- workspace layout ----
  size_t NPel = (size_t)NP * HD;
  size_t nel  = (size_t)N * HD;
  unsigned short* b0 = (unsigned short*)d_ws;  // h1 (padded, row-major) / agg slabs
  unsigned short* b1 = b0 + NPel;              // x slabs
  unsigned short* b3 = b1 + nel;               // x slabs (next)
  int*  gcnt = (int*)(b3 + nel);               // 256 ints
  int*  ebuf = gcnt + 256;                     // NB*CAP packed edges
  int*  csr  = ebuf + (size_t)NB * CAP;
  int*  offs = csr + (size_t)NB * CAP;
  int*  deg  = offs + N;
  float* inv_deg = (float*)(deg + N);
  float* zl = inv_deg + N;
  float* zr = zl + N;
  int*  invp = (int*)(zr + N);
  uintptr_t wp_addr = ((uintptr_t)(invp + N) + 15) & ~(uintptr_t)15;
  unsigned short* Wp = (unsigned short*)wp_addr;   // 4*16384 + 3*32768 bf16

  // ---- weight repack + invptv + gcnt zero (one launch) ----
  wprep_all_kernel<<<640, 256, 0, stream>>>(Wg2, Wld2, Wor2, Wex2, Wl_h, Wr_h, Wp,
                                            ptv, invp, gcnt, N);

  // ---- embeddings ----
  embed1_kernel<<<NP / 2, 256, 0, stream>>>(x_gen, x_load, x_or, x_ex,
                                            Wg1, bg1, Wld1, bld1, Wor1, bor1, Wex1, bex1,
                                            b0, padCum, realCnt);
  mfma_embed2_kernel<<<NP / 64, 256, 0, stream>>>(b0, Wp, bg2, bld2, bor2, bex2,
                                                  invp, b1, padCum, realStart, realCnt, N16);

  // ---- CSR build (bucketed, LDS-local atomics) ----
  bucket_scatter_kernel<<<(nE + SCHUNK - 1) / SCHUNK, 256, 0, stream>>>(esrc, edst, gcnt, ebuf, nE);
  bucket_build_kernel<<<NB, 256, 0, stream>>>(ebuf, gcnt, csr, offs, deg, inv_deg, N);

  // ---- hidden SAGE layers ----
  const int aggGrid = ((N + 63) / 64) * 8;
  const unsigned short* WpC = Wp + 4 * 16384;
  unsigned short* xcur = b1;
  unsigned short* xnext = b3;
  for (int l = 0; l < 2; l++) {
    agg_slab_kernel<<<aggGrid, 256, 0, stream>>>(xcur, csr, offs, deg, inv_deg, b0, N, N16);
    mfma_comb_kernel<false><<<(N + 63) / 64, 256, 0, stream>>>(
        b0, xcur, WpC + (size_t)l * 32768, bl_h + (size_t)l * HD, xnext,
        nullptr, nullptr, nullptr, nullptr, N, N16);
    unsigned short* tmp = xcur; xcur = xnext; xnext = tmp;
  }
  // layer 3 fused with output projection (zl = x3.Wl_o, zr = x3.Wr_o)
  agg_slab_kernel<<<aggGrid, 256, 0, stream>>>(xcur, csr, offs, deg, inv_deg, b0, N, N16);
  mfma_comb_kernel<true><<<(N + 63) / 64, 256, 0, stream>>>(
      b0, xcur, WpC + 2 * 32768, bl_h + 2 * HD, nullptr,
      Wl_o, Wr_o, zl, zr, N, N16);

  // ---- final scalar aggregation + sigmoid ----
  zfinal_kernel<<<(N + 255) / 256, 256, 0, stream>>>(zl, zr, csr, offs, deg, inv_deg,
                                                     bl_o, (float*)d_out, N);
}

// Round 5
// 432.337 us; speedup vs baseline: 2.1296x; 2.1296x over previous
//
#include <hip/hip_runtime.h>
#include <hip/hip_bf16.h>
#include <math.h>

#define HD 128
#define NPB 512        // nodes per bucket
#define CAP 16384      // edge capacity per bucket (avg ~8163 -> 2x headroom)
#define SCHUNK 4096    // edges per scatter block
#define LCSR_CAP 1536  // staged csr entries per 32-node block (avg ~512)

typedef __attribute__((ext_vector_type(8))) short  bf16x8;
typedef __attribute__((ext_vector_type(4))) float  f32x4;
typedef __attribute__((ext_vector_type(8))) unsigned short ushort8;

__device__ __forceinline__ float lrelu(float v) { return v > 0.0f ? v : 0.1f * v; }

__device__ __forceinline__ unsigned short f2bf(float f) {
  union { float f; unsigned u; } c; c.f = f;
  unsigned u = c.u + 0x7fffu + ((c.u >> 16) & 1u);   // RNE
  return (unsigned short)(u >> 16);
}
__device__ __forceinline__ float bf2f(unsigned short u) {
  return __uint_as_float((unsigned)u << 16);
}

// slab layout: act[s][node][16] for s=0..7; element (node, col) at
// slab(col>>4) * N16 + node*16 + (col&15), N16 = N*16.

// ---------------- embedding layer 1 (all types, padded node ids) ----------------
__global__ __launch_bounds__(256)
void embed1_kernel(const float* __restrict__ xg, const float* __restrict__ xl,
                   const float* __restrict__ xo, const float* __restrict__ xe,
                   const float* __restrict__ Wg, const float* __restrict__ bg,
                   const float* __restrict__ Wl, const float* __restrict__ bl,
                   const float* __restrict__ Wo, const float* __restrict__ bo,
                   const float* __restrict__ We, const float* __restrict__ be,
                   unsigned short* __restrict__ h1, int4 padCum, int4 realCnt) {
  int p = blockIdx.x * 2 + (threadIdx.x >> 7);
  if (p >= padCum.w) return;
  int j = threadIdx.x & 127;
  int typ = (p < padCum.x) ? 0 : (p < padCum.y) ? 1 : (p < padCum.z) ? 2 : 3;
  int padStart = (typ == 0) ? 0 : (typ == 1) ? padCum.x : (typ == 2) ? padCum.y : padCum.z;
  int cnt = (typ == 0) ? realCnt.x : (typ == 1) ? realCnt.y : (typ == 2) ? realCnt.z : realCnt.w;
  int loc = p - padStart;
  if (loc >= cnt) return;
  const float *x, *W, *bb; int IN;
  if (typ == 0)      { x = xg; W = Wg; bb = bg; IN = 3; }
  else if (typ == 1) { x = xl; W = Wl; bb = bl; IN = 3; }
  else if (typ == 2) { x = xo; W = Wo; bb = bo; IN = 6; }
  else               { x = xe; W = We; bb = be; IN = 6; }
  float acc = bb[j];
  for (int k = 0; k < IN; k++) acc += x[(size_t)loc * IN + k] * W[k * HD + j];
  h1[(size_t)p * HD + j] = f2bf(lrelu(acc));
}

// ---------------- weight repack + invptv + gcnt zero ----------------
__global__ __launch_bounds__(256)
void wprep_all_kernel(const float* __restrict__ Wg2, const float* __restrict__ Wld2,
                      const float* __restrict__ Wor2, const float* __restrict__ Wex2,
                      const float* __restrict__ Wl_h, const float* __restrict__ Wr_h,
                      unsigned short* __restrict__ Wp,
                      const int* __restrict__ ptv, int* __restrict__ inv,
                      int* __restrict__ gcnt, int n) {
  int tid = blockIdx.x * 256 + threadIdx.x;      // 10 * 16384 total
  if (tid < 256) gcnt[tid] = 0;
  if (tid < n) inv[ptv[tid]] = tid;
  int m = tid >> 14;
  int i = tid & 16383;
  const float* src; unsigned short* dst;
  switch (m) {
    case 0: src = Wg2;  dst = Wp;             break;
    case 1: src = Wld2; dst = Wp + 16384;     break;
    case 2: src = Wor2; dst = Wp + 2 * 16384; break;
    case 3: src = Wex2; dst = Wp + 3 * 16384; break;
    default: {
      int mm = m - 4; int l = mm >> 1; int isR = mm & 1;
      src = (isR ? Wr_h : Wl_h) + (size_t)l * 16384;
      dst = Wp + 4 * 16384 + (size_t)l * 32768 + (isR ? 16384 : 0);
    }
  }
  int k = i >> 7, j = i & 127;
  int ks = k >> 5, g = (k >> 3) & 3, b = k & 7;
  dst[((ks * 128 + j) * 4 + g) * 8 + b] = f2bf(src[i]);
}

// ---------------- embedding layer 2 (MFMA), h1 row-major -> slab out ----------------
__global__ __launch_bounds__(256)
void mfma_embed2_kernel(const unsigned short* __restrict__ h1,
                        const unsigned short* __restrict__ Wp,
                        const float* __restrict__ b_g, const float* __restrict__ b_ld,
                        const float* __restrict__ b_or, const float* __restrict__ b_ex,
                        const int* __restrict__ inv, unsigned short* __restrict__ out,
                        int4 padCum, int4 realStart, int4 realCnt, int N16) {
  const int t = threadIdx.x, w = t >> 6, l = t & 63;
  const int lr = l & 15, lg = l >> 4;
  const int prow0 = blockIdx.x * 64 + w * 16;
  int typ = (prow0 < padCum.x) ? 0 : (prow0 < padCum.y) ? 1 : (prow0 < padCum.z) ? 2 : 3;
  int padStart = (typ == 0) ? 0 : (typ == 1) ? padCum.x : (typ == 2) ? padCum.y : padCum.z;
  int rStart = (typ == 0) ? realStart.x : (typ == 1) ? realStart.y : (typ == 2) ? realStart.z : realStart.w;
  int cnt = (typ == 0) ? realCnt.x : (typ == 1) ? realCnt.y : (typ == 2) ? realCnt.z : realCnt.w;
  const float* bias = (typ == 0) ? b_g : (typ == 1) ? b_ld : (typ == 2) ? b_or : b_ex;

  int raLoc = prow0 + lr - padStart; if (raLoc >= cnt) raLoc = cnt - 1;
  const unsigned short* abase = h1 + (size_t)(padStart + raLoc) * HD + 8 * lg;
  const unsigned short* wbase = Wp + (size_t)typ * 16384 + lr * 32 + lg * 8;

  f32x4 acc[8];
  #pragma unroll
  for (int cb = 0; cb < 8; cb++) {
    float bv = bias[cb * 16 + lr];
    acc[cb] = (f32x4){bv, bv, bv, bv};
  }
  #pragma unroll
  for (int ks = 0; ks < 4; ks++) {
    bf16x8 af = *(const bf16x8*)(abase + ks * 32);
    #pragma unroll
    for (int cb = 0; cb < 8; cb++) {
      bf16x8 bfv = *(const bf16x8*)(wbase + (size_t)(ks * 128 + cb * 16) * 32);
      acc[cb] = __builtin_amdgcn_mfma_f32_16x16x32_bf16(af, bfv, acc[cb], 0, 0, 0);
    }
  }
  int tgt[4];
  #pragma unroll
  for (int r = 0; r < 4; r++) {
    int locRow = prow0 + lg * 4 + r - padStart;
    tgt[r] = (locRow < cnt) ? inv[rStart + locRow] : -1;
  }
  #pragma unroll
  for (int cb = 0; cb < 8; cb++) {
    #pragma unroll
    for (int r = 0; r < 4; r++) {
      if (tgt[r] >= 0)
        out[(size_t)cb * N16 + (size_t)tgt[r] * 16 + lr] = f2bf(lrelu(acc[cb][r]));
    }
  }
}

// ---------------- MFMA combine (slab in, slab out / z out) ----------------
template<bool EMIT_Z>
__global__ __launch_bounds__(256)
void mfma_comb_kernel(const unsigned short* __restrict__ Aa, const unsigned short* __restrict__ Ab,
                      const unsigned short* __restrict__ Wp, const float* __restrict__ bias,
                      unsigned short* __restrict__ out,
                      const float* __restrict__ wl, const float* __restrict__ wr,
                      float* __restrict__ zl, float* __restrict__ zr,
                      int n_rows, int N16) {
  const int t = threadIdx.x;
  const int w = t >> 6;
  const int l = t & 63;
  const int lr = l & 15;
  const int lg = l >> 4;
  const int row0 = blockIdx.x * 64 + w * 16;
  int ra = row0 + lr; if (ra >= n_rows) ra = n_rows - 1;

  const unsigned short* wbase = Wp + (size_t)lr * 32 + (size_t)lg * 8;
  const unsigned short* abase = Aa + (size_t)(lg >> 1) * N16 + (size_t)ra * 16 + (lg & 1) * 8;
  const unsigned short* bbase = Ab + (size_t)(lg >> 1) * N16 + (size_t)ra * 16 + (lg & 1) * 8;

  f32x4 acc[8];
  #pragma unroll
  for (int cb = 0; cb < 8; cb++) {
    float bv = bias[cb * 16 + lr];
    acc[cb] = (f32x4){bv, bv, bv, bv};
  }
  #pragma unroll
  for (int ks = 0; ks < 4; ks++) {
    bf16x8 af = *(const bf16x8*)(abase + (size_t)(2 * ks) * N16);
    #pragma unroll
    for (int cb = 0; cb < 8; cb++) {
      bf16x8 bfv = *(const bf16x8*)(wbase + (size_t)(ks * 128 + cb * 16) * 32);
      acc[cb] = __builtin_amdgcn_mfma_f32_16x16x32_bf16(af, bfv, acc[cb], 0, 0, 0);
    }
  }
  #pragma unroll
  for (int ks = 0; ks < 4; ks++) {
    bf16x8 af = *(const bf16x8*)(bbase + (size_t)(2 * ks) * N16);
    #pragma unroll
    for (int cb = 0; cb < 8; cb++) {
      bf16x8 bfv = *(const bf16x8*)(wbase + (size_t)((4 + ks) * 128 + cb * 16) * 32);
      acc[cb] = __builtin_amdgcn_mfma_f32_16x16x32_bf16(af, bfv, acc[cb], 0, 0, 0);
    }
  }

  if constexpr (!EMIT_Z) {
    #pragma unroll
    for (int cb = 0; cb < 8; cb++) {
      #pragma unroll
      for (int r = 0; r < 4; r++) {
        int node = row0 + lg * 4 + r;
        if (node < n_rows)
          out[(size_t)cb * N16 + (size_t)node * 16 + lr] = f2bf(lrelu(acc[cb][r]));
      }
    }
  } else {
    float vl[4] = {0.f, 0.f, 0.f, 0.f}, vr[4] = {0.f, 0.f, 0.f, 0.f};
    #pragma unroll
    for (int cb = 0; cb < 8; cb++) {
      float wlv = wl[cb * 16 + lr];
      float wrv = wr[cb * 16 + lr];
      #pragma unroll
      for (int r = 0; r < 4; r++) {
        float x3 = lrelu(acc[cb][r]);
        vl[r] += x3 * wlv;
        vr[r] += x3 * wrv;
      }
    }
    #pragma unroll
    for (int r = 0; r < 4; r++) {
      #pragma unroll
      for (int d = 1; d < 16; d <<= 1) {
        vl[r] += __shfl_xor(vl[r], d, 64);
        vr[r] += __shfl_xor(vr[r], d, 64);
      }
    }
    if (lr == 0) {
      #pragma unroll
      for (int r = 0; r < 4; r++) {
        int node = row0 + lg * 4 + r;
        if (node < n_rows) { zl[node] = vl[r]; zr[node] = vr[r]; }
      }
    }
  }
}

// ---------------- CSR build phase 1: bucket scatter (packed int) ----------------
__global__ __launch_bounds__(256)
void bucket_scatter_kernel(const int* __restrict__ esrc, const int* __restrict__ edst,
                           int* __restrict__ gcnt, int* __restrict__ ebuf, int nE) {
  __shared__ int cnt[256];
  __shared__ int cur[256];
  const int t = threadIdx.x;
  const int c0 = blockIdx.x * SCHUNK;
  int s_arr[16], d_arr[16];
  cnt[t] = 0;
  __syncthreads();
  #pragma unroll
  for (int k = 0; k < 16; k++) {
    int idx = c0 + k * 256 + t;
    if (idx < nE) {
      s_arr[k] = esrc[idx];
      int d = edst[idx];
      d_arr[k] = d;
      atomicAdd(&cnt[d >> 9], 1);
    } else d_arr[k] = -1;
  }
  __syncthreads();
  if (cnt[t] > 0) cur[t] = atomicAdd(&gcnt[t], cnt[t]);
  __syncthreads();
  #pragma unroll
  for (int k = 0; k < 16; k++) {
    if (d_arr[k] >= 0) {
      int b = d_arr[k] >> 9;
      int p = atomicAdd(&cur[b], 1);
      ebuf[(size_t)b * CAP + p] = (s_arr[k] << 9) | (d_arr[k] & 511);
    }
  }
}

__device__ __forceinline__ int wave_incl_scan(int v) {
  int lane = threadIdx.x & 63;
  #pragma unroll
  for (int d = 1; d < 64; d <<= 1) {
    int tv = __shfl_up(v, d, 64);
    if (lane >= d) v += tv;
  }
  return v;
}

// ---------------- CSR build phase 2: per-bucket local build ----------------
__global__ __launch_bounds__(256)
void bucket_build_kernel(const int* __restrict__ ebuf, const int* __restrict__ gcnt,
                         int* __restrict__ csr, int* __restrict__ offs,
                         int* __restrict__ deg, float* __restrict__ inv_deg, int n) {
  __shared__ int hist[512];
  __shared__ int offl[512];
  __shared__ int wsum[4];
  const int b = blockIdx.x, t = threadIdx.x;
  const int cnt = gcnt[b];
  const size_t ebase = (size_t)b * CAP;
  hist[t] = 0; hist[t + 256] = 0;
  __syncthreads();
  for (int i = t; i < cnt; i += 256) {
    int e = ebuf[ebase + i];
    atomicAdd(&hist[e & 511], 1);
  }
  __syncthreads();
  int a0 = hist[2 * t], a1 = hist[2 * t + 1];
  int s = a0 + a1;
  int incl = wave_incl_scan(s);
  int wid = t >> 6;
  if ((t & 63) == 63) wsum[wid] = incl;
  __syncthreads();
  int wbase = 0;
  for (int w_ = 0; w_ < wid; w_++) wbase += wsum[w_];
  int excl = wbase + incl - s;
  offl[2 * t] = excl;
  offl[2 * t + 1] = excl + a0;
  __syncthreads();
  const int d0 = b << 9;
  for (int i = t; i < 512; i += 256) {
    int g = d0 + i;
    if (g < n) {
      offs[g] = b * CAP + offl[i];
      int dg = hist[i];
      deg[g] = dg;
      inv_deg[g] = 1.0f / fmaxf((float)dg, 1.0f);
    }
  }
  __syncthreads();
  for (int i = t; i < cnt; i += 256) {
    int e = ebuf[ebase + i];
    int p = atomicAdd(&offl[e & 511], 1);
    csr[ebase + p] = ((unsigned)e) >> 9;
  }
}

// ---------------- mean aggregation v2: slab-sliced, XCD-affine, LDS csr ----------------
// blockIdx.x = chunk*8 + slice; slice -> XCD under round-robin dispatch so each
// XCD gathers only its own 3.2MB slab (L2-resident). 32 nodes per block.
// Lane = (g: node 0..7, s: edge-stripe 0..3, h: col-half 0..1); 16B loads.
__global__ __launch_bounds__(256)
void agg_slab_kernel(const unsigned short* __restrict__ x, const int* __restrict__ csr,
                     const int* __restrict__ offs, const int* __restrict__ deg,
                     const float* __restrict__ inv_deg, unsigned short* __restrict__ agg,
                     int n, int N16) {
  __shared__ int lcsr[LCSR_CAP];
  const int slice = blockIdx.x & 7;
  const int chunk = blockIdx.x >> 3;
  const int t = threadIdx.x;
  const int node0 = chunk * 32;

  int last = node0 + 31; if (last >= n) last = n - 1;
  const int s_begin = offs[node0];
  const int total = offs[last] + deg[last] - s_begin;   // contiguous: 32 | NPB
  const bool useLds = (total <= LCSR_CAP);
  if (useLds) {
    for (int k = t; k < total; k += 256) lcsr[k] = csr[s_begin + k];
  }
  __syncthreads();

  const int w = t >> 6, l = t & 63;
  const int g = l >> 3, s = (l >> 1) & 3, h = l & 1;
  const int node = node0 + w * 8 + g;
  if (node >= n) return;
  const unsigned short* xs = x + (size_t)slice * N16 + 8 * h;
  const int lbase = offs[node] - s_begin;
  const int d = deg[node];

  float acc[8] = {0.f,0.f,0.f,0.f,0.f,0.f,0.f,0.f};
  if (useLds) {
    for (int i = s; i < d; i += 4) {
      int src = lcsr[lbase + i];
      ushort8 v = *(const ushort8*)(xs + (size_t)src * 16);
      #pragma unroll
      for (int q = 0; q < 8; q++) acc[q] += bf2f(v[q]);
    }
  } else {
    for (int i = s; i < d; i += 4) {
      int src = csr[s_begin + lbase + i];
      ushort8 v = *(const ushort8*)(xs + (size_t)src * 16);
      #pragma unroll
      for (int q = 0; q < 8; q++) acc[q] += bf2f(v[q]);
    }
  }
  #pragma unroll
  for (int q = 0; q < 8; q++) {
    acc[q] += __shfl_xor(acc[q], 2, 64);
    acc[q] += __shfl_xor(acc[q], 4, 64);
  }
  if ((l & 6) == 0) {
    float id = inv_deg[node];
    ushort8 o;
    #pragma unroll
    for (int q = 0; q < 8; q++) o[q] = f2bf(acc[q] * id);
    *(ushort8*)(agg + (size_t)slice * N16 + (size_t)node * 16 + 8 * h) = o;
  }
}

// ---------------- final: out = sigmoid(mean(zl) + zr + bl) ----------------
__global__ __launch_bounds__(256)
void zfinal_kernel(const float* __restrict__ zl, const float* __restrict__ zr,
                   const int* __restrict__ csr, const int* __restrict__ offs,
                   const int* __restrict__ deg, const float* __restrict__ inv_deg,
                   const float* __restrict__ bl, float* __restrict__ out, int n) {
  int i = blockIdx.x * 256 + threadIdx.x;
  if (i >= n) return;
  int s0 = offs[i], d = deg[i];
  float a = 0.f;
  #pragma unroll 4
  for (int e = 0; e < d; e++) a += zl[csr[s0 + e]];
  float s = a * inv_deg[i] + bl[0] + zr[i];
  out[i] = 1.0f / (1.0f + expf(-s));
}

extern "C" void kernel_launch(void* const* d_in, const int* in_sizes, int n_in,
                              void* d_out, int out_size, void* d_ws, size_t ws_size,
                              hipStream_t stream) {
  const float* x_gen  = (const float*)d_in[0];
  const float* x_load = (const float*)d_in[1];
  const float* x_or   = (const float*)d_in[2];
  const float* x_ex   = (const float*)d_in[3];
  const int*   edge   = (const int*)d_in[4];
  const int*   ptv    = (const int*)d_in[5];
  const float* Wg1  = (const float*)d_in[6],  *bg1  = (const float*)d_in[7];
  const float* Wg2  = (const float*)d_in[8],  *bg2  = (const float*)d_in[9];
  const float* Wld1 = (const float*)d_in[10], *bld1 = (const float*)d_in[11];
  const float* Wld2 = (const float*)d_in[12], *bld2 = (const float*)d_in[13];
  const float* Wor1 = (const float*)d_in[14], *bor1 = (const float*)d_in[15];
  const float* Wor2 = (const float*)d_in[16], *bor2 = (const float*)d_in[17];
  const float* Wex1 = (const float*)d_in[18], *bex1 = (const float*)d_in[19];
  const float* Wex2 = (const float*)d_in[20], *bex2 = (const float*)d_in[21];
  const float* Wl_h = (const float*)d_in[22], *bl_h = (const float*)d_in[23];
  const float* Wr_h = (const float*)d_in[24];
  const float* Wl_o = (const float*)d_in[25], *bl_o = (const float*)d_in[26];
  const float* Wr_o = (const float*)d_in[27];

  const int n_gen  = in_sizes[0] / 3;
  const int n_load = in_sizes[1] / 3;
  const int n_or   = in_sizes[2] / 6;
  const int n_ex   = in_sizes[3] / 6;
  const int nE     = in_sizes[4] / 2;
  const int N      = in_sizes[5];
  const int* esrc = edge;
  const int* edst = edge + nE;

  // padded segment geometry (each segment rounded to 64 rows)
  const int np0 = ((n_gen  + 63) / 64) * 64;
  const int np1 = ((n_load + 63) / 64) * 64;
  const int np2 = ((n_or   + 63) / 64) * 64;
  const int np3 = ((n_ex   + 63) / 64) * 64;
  const int NP  = np0 + np1 + np2 + np3;
  const int4 padCum    = make_int4(np0, np0 + np1, np0 + np1 + np2, NP);
  const int4 realStart = make_int4(0, n_gen, n_gen + n_load, n_gen + n_load + n_or);
  const int4 realCnt   = make_int4(n_gen, n_load, n_or, n_ex);
  const int N16 = N * 16;

  const int NB = (N + NPB - 1) / NPB;   // buckets (<=256 for N<=131072)

  // ---- workspace layout ----
  size_t NPel = (size_t)NP * HD;
  size_t nel  = (size_t)N * HD;
  unsigned short* b0 = (unsigned short*)d_ws;  // h1 (padded, row-major) / agg slabs
  unsigned short* b1 = b0 + NPel;              // x slabs
  unsigned short* b3 = b1 + nel;               // x slabs (next)
  int*  gcnt = (int*)(b3 + nel);               // 256 ints
  int*  ebuf = gcnt + 256;                     // NB*CAP packed edges
  int*  csr  = ebuf + (size_t)NB * CAP;
  int*  offs = csr + (size_t)NB * CAP;
  int*  deg  = offs + N;
  float* inv_deg = (float*)(deg + N);
  float* zl = inv_deg + N;
  float* zr = zl + N;
  int*  invp = (int*)(zr + N);
  uintptr_t wp_addr = ((uintptr_t)(invp + N) + 15) & ~(uintptr_t)15;
  unsigned short* Wp = (unsigned short*)wp_addr;   // 4*16384 + 3*32768 bf16

  // ---- weight repack + invptv + gcnt zero (one launch) ----
  wprep_all_kernel<<<640, 256, 0, stream>>>(Wg2, Wld2, Wor2, Wex2, Wl_h, Wr_h, Wp,
                                            ptv, invp, gcnt, N);

  // ---- embeddings ----
  embed1_kernel<<<NP / 2, 256, 0, stream>>>(x_gen, x_load, x_or, x_ex,
                                            Wg1, bg1, Wld1, bld1, Wor1, bor1, Wex1, bex1,
                                            b0, padCum, realCnt);
  mfma_embed2_kernel<<<NP / 64, 256, 0, stream>>>(b0, Wp, bg2, bld2, bor2, bex2,
                                                  invp, b1, padCum, realStart, realCnt, N16);

  // ---- CSR build (bucketed, LDS-local atomics) ----
  bucket_scatter_kernel<<<(nE + SCHUNK - 1) / SCHUNK, 256, 0, stream>>>(esrc, edst, gcnt, ebuf, nE);
  bucket_build_kernel<<<NB, 256, 0, stream>>>(ebuf, gcnt, csr, offs, deg, inv_deg, N);

  // ---- hidden SAGE layers ----
  const int aggGrid = ((N + 31) / 32) * 8;
  const unsigned short* WpC = Wp + 4 * 16384;
  unsigned short* xcur = b1;
  unsigned short* xnext = b3;
  for (int l = 0; l < 2; l++) {
    agg_slab_kernel<<<aggGrid, 256, 0, stream>>>(xcur, csr, offs, deg, inv_deg, b0, N, N16);
    mfma_comb_kernel<false><<<(N + 63) / 64, 256, 0, stream>>>(
        b0, xcur, WpC + (size_t)l * 32768, bl_h + (size_t)l * HD, xnext,
        nullptr, nullptr, nullptr, nullptr, N, N16);
    unsigned short* tmp = xcur; xcur = xnext; xnext = tmp;
  }
  // layer 3 fused with output projection (zl = x3.Wl_o, zr = x3.Wr_o)
  agg_slab_kernel<<<aggGrid, 256, 0, stream>>>(xcur, csr, offs, deg, inv_deg, b0, N, N16);
  mfma_comb_kernel<true><<<(N + 63) / 64, 256, 0, stream>>>(
      b0, xcur, WpC + 2 * 32768, bl_h + 2 * HD, nullptr,
      Wl_o, Wr_o, zl, zr, N, N16);

  // ---- final scalar aggregation + sigmoid ----
  zfinal_kernel<<<(N + 255) / 256, 256, 0, stream>>>(zl, zr, csr, offs, deg, inv_deg,
                                                     bl_o, (float*)d_out, N);
}

// Round 6
// 403.038 us; speedup vs baseline: 2.2844x; 1.0727x over previous
//
#include <hip/hip_runtime.h>
#include <hip/hip_bf16.h>
#include <math.h>

#define HD 128
#define NPB 512        // nodes per bucket
#define CAP 16384      // edge capacity per bucket (avg ~8163 -> 2x headroom)
#define SCHUNK 4096    // edges per scatter block
#define ALCSR 768      // staged csr entries per 16-node agg block (avg ~256)

typedef __attribute__((ext_vector_type(8))) short  bf16x8;
typedef __attribute__((ext_vector_type(4))) float  f32x4;

__device__ __forceinline__ float lrelu(float v) { return v > 0.0f ? v : 0.1f * v; }

__device__ __forceinline__ unsigned short f2bf(float f) {
  union { float f; unsigned u; } c; c.f = f;
  unsigned u = c.u + 0x7fffu + ((c.u >> 16) & 1u);   // RNE
  return (unsigned short)(u >> 16);
}
__device__ __forceinline__ float bf2f(unsigned short u) {
  return __uint_as_float((unsigned)u << 16);
}

// ---------------- embedding layer 1 (all types, padded node ids) ----------------
__global__ __launch_bounds__(256)
void embed1_kernel(const float* __restrict__ xg, const float* __restrict__ xl,
                   const float* __restrict__ xo, const float* __restrict__ xe,
                   const float* __restrict__ Wg, const float* __restrict__ bg,
                   const float* __restrict__ Wl, const float* __restrict__ bl,
                   const float* __restrict__ Wo, const float* __restrict__ bo,
                   const float* __restrict__ We, const float* __restrict__ be,
                   unsigned short* __restrict__ h1, int4 padCum, int4 realCnt) {
  int p = blockIdx.x * 2 + (threadIdx.x >> 7);
  if (p >= padCum.w) return;
  int j = threadIdx.x & 127;
  int typ = (p < padCum.x) ? 0 : (p < padCum.y) ? 1 : (p < padCum.z) ? 2 : 3;
  int padStart = (typ == 0) ? 0 : (typ == 1) ? padCum.x : (typ == 2) ? padCum.y : padCum.z;
  int cnt = (typ == 0) ? realCnt.x : (typ == 1) ? realCnt.y : (typ == 2) ? realCnt.z : realCnt.w;
  int loc = p - padStart;
  if (loc >= cnt) return;
  const float *x, *W, *bb; int IN;
  if (typ == 0)      { x = xg; W = Wg; bb = bg; IN = 3; }
  else if (typ == 1) { x = xl; W = Wl; bb = bl; IN = 3; }
  else if (typ == 2) { x = xo; W = Wo; bb = bo; IN = 6; }
  else               { x = xe; W = We; bb = be; IN = 6; }
  float acc = bb[j];
  for (int k = 0; k < IN; k++) acc += x[(size_t)loc * IN + k] * W[k * HD + j];
  h1[(size_t)p * HD + j] = f2bf(lrelu(acc));
}

// ---------------- weight repack + invptv + gcnt zero ----------------
__global__ __launch_bounds__(256)
void wprep_all_kernel(const float* __restrict__ Wg2, const float* __restrict__ Wld2,
                      const float* __restrict__ Wor2, const float* __restrict__ Wex2,
                      const float* __restrict__ Wl_h, const float* __restrict__ Wr_h,
                      unsigned short* __restrict__ Wp,
                      const int* __restrict__ ptv, int* __restrict__ inv,
                      int* __restrict__ gcnt, int n) {
  int tid = blockIdx.x * 256 + threadIdx.x;      // 10 * 16384 total
  if (tid < 256) gcnt[tid] = 0;
  if (tid < n) inv[ptv[tid]] = tid;
  int m = tid >> 14;
  int i = tid & 16383;
  const float* src; unsigned short* dst;
  switch (m) {
    case 0: src = Wg2;  dst = Wp;             break;
    case 1: src = Wld2; dst = Wp + 16384;     break;
    case 2: src = Wor2; dst = Wp + 2 * 16384; break;
    case 3: src = Wex2; dst = Wp + 3 * 16384; break;
    default: {
      int mm = m - 4; int l = mm >> 1; int isR = mm & 1;
      src = (isR ? Wr_h : Wl_h) + (size_t)l * 16384;
      dst = Wp + 4 * 16384 + (size_t)l * 32768 + (isR ? 16384 : 0);
    }
  }
  int k = i >> 7, j = i & 127;
  int ks = k >> 5, g = (k >> 3) & 3, b = k & 7;
  dst[((ks * 128 + j) * 4 + g) * 8 + b] = f2bf(src[i]);
}

// ---------------- embedding layer 2 (MFMA), row-major out via invp ----------------
__global__ __launch_bounds__(256)
void mfma_embed2_kernel(const unsigned short* __restrict__ h1,
                        const unsigned short* __restrict__ Wp,
                        const float* __restrict__ b_g, const float* __restrict__ b_ld,
                        const float* __restrict__ b_or, const float* __restrict__ b_ex,
                        const int* __restrict__ inv, unsigned short* __restrict__ out,
                        int4 padCum, int4 realStart, int4 realCnt) {
  const int t = threadIdx.x, w = t >> 6, l = t & 63;
  const int lr = l & 15, lg = l >> 4;
  const int prow0 = blockIdx.x * 64 + w * 16;
  int typ = (prow0 < padCum.x) ? 0 : (prow0 < padCum.y) ? 1 : (prow0 < padCum.z) ? 2 : 3;
  int padStart = (typ == 0) ? 0 : (typ == 1) ? padCum.x : (typ == 2) ? padCum.y : padCum.z;
  int rStart = (typ == 0) ? realStart.x : (typ == 1) ? realStart.y : (typ == 2) ? realStart.z : realStart.w;
  int cnt = (typ == 0) ? realCnt.x : (typ == 1) ? realCnt.y : (typ == 2) ? realCnt.z : realCnt.w;
  const float* bias = (typ == 0) ? b_g : (typ == 1) ? b_ld : (typ == 2) ? b_or : b_ex;

  int raLoc = prow0 + lr - padStart; if (raLoc >= cnt) raLoc = cnt - 1;
  const unsigned short* abase = h1 + (size_t)(padStart + raLoc) * HD + 8 * lg;
  const unsigned short* wbase = Wp + (size_t)typ * 16384 + lr * 32 + lg * 8;

  f32x4 acc[8];
  #pragma unroll
  for (int cb = 0; cb < 8; cb++) {
    float bv = bias[cb * 16 + lr];
    acc[cb] = (f32x4){bv, bv, bv, bv};
  }
  #pragma unroll
  for (int ks = 0; ks < 4; ks++) {
    bf16x8 af = *(const bf16x8*)(abase + ks * 32);
    #pragma unroll
    for (int cb = 0; cb < 8; cb++) {
      bf16x8 bfv = *(const bf16x8*)(wbase + (size_t)(ks * 128 + cb * 16) * 32);
      acc[cb] = __builtin_amdgcn_mfma_f32_16x16x32_bf16(af, bfv, acc[cb], 0, 0, 0);
    }
  }
  int tgt[4];
  #pragma unroll
  for (int r = 0; r < 4; r++) {
    int locRow = prow0 + lg * 4 + r - padStart;
    tgt[r] = (locRow < cnt) ? inv[rStart + locRow] : -1;
  }
  #pragma unroll
  for (int cb = 0; cb < 8; cb++) {
    #pragma unroll
    for (int r = 0; r < 4; r++) {
      if (tgt[r] >= 0)
        out[(size_t)tgt[r] * HD + cb * 16 + lr] = f2bf(lrelu(acc[cb][r]));
    }
  }
}

// ---------------- MFMA combine (row-major), optional fused output projection ----------------
template<bool EMIT_Z>
__global__ __launch_bounds__(256)
void mfma_comb_kernel(const unsigned short* __restrict__ Aa, const unsigned short* __restrict__ Ab,
                      const unsigned short* __restrict__ Wp, const float* __restrict__ bias,
                      unsigned short* __restrict__ out,
                      const float* __restrict__ wl, const float* __restrict__ wr,
                      float* __restrict__ zl, float* __restrict__ zr, int n_rows) {
  const int t = threadIdx.x;
  const int w = t >> 6;
  const int l = t & 63;
  const int lr = l & 15;
  const int lg = l >> 4;
  const int row0 = blockIdx.x * 64 + w * 16;
  int ra = row0 + lr; if (ra >= n_rows) ra = n_rows - 1;

  const unsigned short* wbase = Wp + (size_t)lr * 32 + (size_t)lg * 8;
  const unsigned short* abase = Aa + (size_t)ra * HD + 8 * lg;
  const unsigned short* bbase = Ab + (size_t)ra * HD + 8 * lg;

  f32x4 acc[8];
  #pragma unroll
  for (int cb = 0; cb < 8; cb++) {
    float bv = bias[cb * 16 + lr];
    acc[cb] = (f32x4){bv, bv, bv, bv};
  }
  #pragma unroll
  for (int ks = 0; ks < 4; ks++) {
    bf16x8 af = *(const bf16x8*)(abase + ks * 32);
    #pragma unroll
    for (int cb = 0; cb < 8; cb++) {
      bf16x8 bfv = *(const bf16x8*)(wbase + (size_t)(ks * 128 + cb * 16) * 32);
      acc[cb] = __builtin_amdgcn_mfma_f32_16x16x32_bf16(af, bfv, acc[cb], 0, 0, 0);
    }
  }
  #pragma unroll
  for (int ks = 0; ks < 4; ks++) {
    bf16x8 af = *(const bf16x8*)(bbase + ks * 32);
    #pragma unroll
    for (int cb = 0; cb < 8; cb++) {
      bf16x8 bfv = *(const bf16x8*)(wbase + (size_t)((4 + ks) * 128 + cb * 16) * 32);
      acc[cb] = __builtin_amdgcn_mfma_f32_16x16x32_bf16(af, bfv, acc[cb], 0, 0, 0);
    }
  }

  if constexpr (!EMIT_Z) {
    #pragma unroll
    for (int cb = 0; cb < 8; cb++) {
      #pragma unroll
      for (int r = 0; r < 4; r++) {
        int node = row0 + lg * 4 + r;
        if (node < n_rows)
          out[(size_t)node * HD + cb * 16 + lr] = f2bf(lrelu(acc[cb][r]));
      }
    }
  } else {
    float vl[4] = {0.f, 0.f, 0.f, 0.f}, vr[4] = {0.f, 0.f, 0.f, 0.f};
    #pragma unroll
    for (int cb = 0; cb < 8; cb++) {
      float wlv = wl[cb * 16 + lr];
      float wrv = wr[cb * 16 + lr];
      #pragma unroll
      for (int r = 0; r < 4; r++) {
        float x3 = lrelu(acc[cb][r]);
        vl[r] += x3 * wlv;
        vr[r] += x3 * wrv;
      }
    }
    #pragma unroll
    for (int r = 0; r < 4; r++) {
      #pragma unroll
      for (int d = 1; d < 16; d <<= 1) {
        vl[r] += __shfl_xor(vl[r], d, 64);
        vr[r] += __shfl_xor(vr[r], d, 64);
      }
    }
    if (lr == 0) {
      #pragma unroll
      for (int r = 0; r < 4; r++) {
        int node = row0 + lg * 4 + r;
        if (node < n_rows) { zl[node] = vl[r]; zr[node] = vr[r]; }
      }
    }
  }
}

// ---------------- CSR build phase 1: bucket scatter (packed int) ----------------
__global__ __launch_bounds__(256)
void bucket_scatter_kernel(const int* __restrict__ esrc, const int* __restrict__ edst,
                           int* __restrict__ gcnt, int* __restrict__ ebuf, int nE) {
  __shared__ int cnt[256];
  __shared__ int cur[256];
  const int t = threadIdx.x;
  const int c0 = blockIdx.x * SCHUNK;
  int s_arr[16], d_arr[16];
  cnt[t] = 0;
  __syncthreads();
  #pragma unroll
  for (int k = 0; k < 16; k++) {
    int idx = c0 + k * 256 + t;
    if (idx < nE) {
      s_arr[k] = esrc[idx];
      int d = edst[idx];
      d_arr[k] = d;
      atomicAdd(&cnt[d >> 9], 1);
    } else d_arr[k] = -1;
  }
  __syncthreads();
  if (cnt[t] > 0) cur[t] = atomicAdd(&gcnt[t], cnt[t]);
  __syncthreads();
  #pragma unroll
  for (int k = 0; k < 16; k++) {
    if (d_arr[k] >= 0) {
      int b = d_arr[k] >> 9;
      int p = atomicAdd(&cur[b], 1);
      ebuf[(size_t)b * CAP + p] = (s_arr[k] << 9) | (d_arr[k] & 511);
    }
  }
}

__device__ __forceinline__ int wave_incl_scan(int v) {
  int lane = threadIdx.x & 63;
  #pragma unroll
  for (int d = 1; d < 64; d <<= 1) {
    int tv = __shfl_up(v, d, 64);
    if (lane >= d) v += tv;
  }
  return v;
}

// ---------------- CSR build phase 2: per-bucket local build ----------------
__global__ __launch_bounds__(256)
void bucket_build_kernel(const int* __restrict__ ebuf, const int* __restrict__ gcnt,
                         int* __restrict__ csr, int* __restrict__ offs,
                         int* __restrict__ deg, float* __restrict__ inv_deg, int n) {
  __shared__ int hist[512];
  __shared__ int offl[512];
  __shared__ int wsum[4];
  const int b = blockIdx.x, t = threadIdx.x;
  const int cnt = gcnt[b];
  const size_t ebase = (size_t)b * CAP;
  hist[t] = 0; hist[t + 256] = 0;
  __syncthreads();
  for (int i = t; i < cnt; i += 256) {
    int e = ebuf[ebase + i];
    atomicAdd(&hist[e & 511], 1);
  }
  __syncthreads();
  int a0 = hist[2 * t], a1 = hist[2 * t + 1];
  int s = a0 + a1;
  int incl = wave_incl_scan(s);
  int wid = t >> 6;
  if ((t & 63) == 63) wsum[wid] = incl;
  __syncthreads();
  int wbase = 0;
  for (int w_ = 0; w_ < wid; w_++) wbase += wsum[w_];
  int excl = wbase + incl - s;
  offl[2 * t] = excl;
  offl[2 * t + 1] = excl + a0;
  __syncthreads();
  const int d0 = b << 9;
  for (int i = t; i < 512; i += 256) {
    int g = d0 + i;
    if (g < n) {
      offs[g] = b * CAP + offl[i];
      int dg = hist[i];
      deg[g] = dg;
      inv_deg[g] = 1.0f / fmaxf((float)dg, 1.0f);
    }
  }
  __syncthreads();
  for (int i = t; i < cnt; i += 256) {
    int e = ebuf[ebase + i];
    int p = atomicAdd(&offl[e & 511], 1);
    csr[ebase + p] = ((unsigned)e) >> 9;
  }
}

// ---------------- mean aggregation: row-major, 16 lanes per node, LDS csr ----------------
// Row reads are 16 lanes x 16B contiguous = 4 fully-used 64B lines per edge
// (the request-rate-minimal pattern). 16 nodes per block, no cross-lane reduce.
__global__ __launch_bounds__(256)
void agg_rm_kernel(const unsigned short* __restrict__ x, const int* __restrict__ csr,
                   const int* __restrict__ offs, const int* __restrict__ deg,
                   const float* __restrict__ inv_deg, unsigned short* __restrict__ agg, int n) {
  __shared__ int lcsr[ALCSR];
  const int t = threadIdx.x;
  const int node0 = blockIdx.x * 16;
  int last = node0 + 15; if (last >= n) last = n - 1;
  const int s_begin = offs[node0];
  const int total = offs[last] + deg[last] - s_begin;   // contiguous: 16 | NPB
  const bool useLds = (total <= ALCSR);
  if (useLds) {
    for (int k = t; k < total; k += 256) lcsr[k] = csr[s_begin + k];
  }
  __syncthreads();

  const int w = t >> 6, l = t & 63;
  const int g = l >> 4, j = l & 15;            // node-in-wave, 8-col group
  const int node = node0 + w * 4 + g;
  if (node >= n) return;
  const unsigned short* xj = x + 8 * j;
  const int lb = offs[node] - s_begin;
  const int d = deg[node];

  float2 a0[4] = {{0.f,0.f},{0.f,0.f},{0.f,0.f},{0.f,0.f}};
  float2 a1[4] = {{0.f,0.f},{0.f,0.f},{0.f,0.f},{0.f,0.f}};
  int i = 0;
  if (useLds) {
    for (; i + 1 < d; i += 2) {
      int e0 = lcsr[lb + i], e1 = lcsr[lb + i + 1];
      uint4 v0 = *(const uint4*)(xj + (size_t)e0 * HD);
      uint4 v1 = *(const uint4*)(xj + (size_t)e1 * HD);
      const unsigned w0[4] = {v0.x, v0.y, v0.z, v0.w};
      const unsigned w1[4] = {v1.x, v1.y, v1.z, v1.w};
      #pragma unroll
      for (int k = 0; k < 4; k++) {
        a0[k] = make_float2(a0[k].x + __uint_as_float(w0[k] << 16),
                            a0[k].y + __uint_as_float(w0[k] & 0xffff0000u));
        a1[k] = make_float2(a1[k].x + __uint_as_float(w1[k] << 16),
                            a1[k].y + __uint_as_float(w1[k] & 0xffff0000u));
      }
    }
    if (i < d) {
      int e0 = lcsr[lb + i];
      uint4 v0 = *(const uint4*)(xj + (size_t)e0 * HD);
      const unsigned w0[4] = {v0.x, v0.y, v0.z, v0.w};
      #pragma unroll
      for (int k = 0; k < 4; k++)
        a0[k] = make_float2(a0[k].x + __uint_as_float(w0[k] << 16),
                            a0[k].y + __uint_as_float(w0[k] & 0xffff0000u));
    }
  } else {
    const int* gcsr = csr + s_begin + lb;
    for (; i + 1 < d; i += 2) {
      int e0 = gcsr[i], e1 = gcsr[i + 1];
      uint4 v0 = *(const uint4*)(xj + (size_t)e0 * HD);
      uint4 v1 = *(const uint4*)(xj + (size_t)e1 * HD);
      const unsigned w0[4] = {v0.x, v0.y, v0.z, v0.w};
      const unsigned w1[4] = {v1.x, v1.y, v1.z, v1.w};
      #pragma unroll
      for (int k = 0; k < 4; k++) {
        a0[k] = make_float2(a0[k].x + __uint_as_float(w0[k] << 16),
                            a0[k].y + __uint_as_float(w0[k] & 0xffff0000u));
        a1[k] = make_float2(a1[k].x + __uint_as_float(w1[k] << 16),
                            a1[k].y + __uint_as_float(w1[k] & 0xffff0000u));
      }
    }
    if (i < d) {
      int e0 = gcsr[i];
      uint4 v0 = *(const uint4*)(xj + (size_t)e0 * HD);
      const unsigned w0[4] = {v0.x, v0.y, v0.z, v0.w};
      #pragma unroll
      for (int k = 0; k < 4; k++)
        a0[k] = make_float2(a0[k].x + __uint_as_float(w0[k] << 16),
                            a0[k].y + __uint_as_float(w0[k] & 0xffff0000u));
    }
  }
  const float id = inv_deg[node];
  uint4 o;
  unsigned* op = (unsigned*)&o;
  #pragma unroll
  for (int k = 0; k < 4; k++) {
    float lo = (a0[k].x + a1[k].x) * id;
    float hi = (a0[k].y + a1[k].y) * id;
    op[k] = (unsigned)f2bf(lo) | ((unsigned)f2bf(hi) << 16);
  }
  *(uint4*)(agg + (size_t)node * HD + 8 * j) = o;
}

// ---------------- final: out = sigmoid(mean(zl) + zr + bl) ----------------
__global__ __launch_bounds__(256)
void zfinal_kernel(const float* __restrict__ zl, const float* __restrict__ zr,
                   const int* __restrict__ csr, const int* __restrict__ offs,
                   const int* __restrict__ deg, const float* __restrict__ inv_deg,
                   const float* __restrict__ bl, float* __restrict__ out, int n) {
  int i = blockIdx.x * 256 + threadIdx.x;
  if (i >= n) return;
  int s0 = offs[i], d = deg[i];
  float a = 0.f;
  #pragma unroll 4
  for (int e = 0; e < d; e++) a += zl[csr[s0 + e]];
  float s = a * inv_deg[i] + bl[0] + zr[i];
  out[i] = 1.0f / (1.0f + expf(-s));
}

extern "C" void kernel_launch(void* const* d_in, const int* in_sizes, int n_in,
                              void* d_out, int out_size, void* d_ws, size_t ws_size,
                              hipStream_t stream) {
  const float* x_gen  = (const float*)d_in[0];
  const float* x_load = (const float*)d_in[1];
  const float* x_or   = (const float*)d_in[2];
  const float* x_ex   = (const float*)d_in[3];
  const int*   edge   = (const int*)d_in[4];
  const int*   ptv    = (const int*)d_in[5];
  const float* Wg1  = (const float*)d_in[6],  *bg1  = (const float*)d_in[7];
  const float* Wg2  = (const float*)d_in[8],  *bg2  = (const float*)d_in[9];
  const float* Wld1 = (const float*)d_in[10], *bld1 = (const float*)d_in[11];
  const float* Wld2 = (const float*)d_in[12], *bld2 = (const float*)d_in[13];
  const float* Wor1 = (const float*)d_in[14], *bor1 = (const float*)d_in[15];
  const float* Wor2 = (const float*)d_in[16], *bor2 = (const float*)d_in[17];
  const float* Wex1 = (const float*)d_in[18], *bex1 = (const float*)d_in[19];
  const float* Wex2 = (const float*)d_in[20], *bex2 = (const float*)d_in[21];
  const float* Wl_h = (const float*)d_in[22], *bl_h = (const float*)d_in[23];
  const float* Wr_h = (const float*)d_in[24];
  const float* Wl_o = (const float*)d_in[25], *bl_o = (const float*)d_in[26];
  const float* Wr_o = (const float*)d_in[27];

  const int n_gen  = in_sizes[0] / 3;
  const int n_load = in_sizes[1] / 3;
  const int n_or   = in_sizes[2] / 6;
  const int n_ex   = in_sizes[3] / 6;
  const int nE     = in_sizes[4] / 2;
  const int N      = in_sizes[5];
  const int* esrc = edge;
  const int* edst = edge + nE;

  // padded segment geometry (each segment rounded to 64 rows)
  const int np0 = ((n_gen  + 63) / 64) * 64;
  const int np1 = ((n_load + 63) / 64) * 64;
  const int np2 = ((n_or   + 63) / 64) * 64;
  const int np3 = ((n_ex   + 63) / 64) * 64;
  const int NP  = np0 + np1 + np2 + np3;
  const int4 padCum    = make_int4(np0, np0 + np1, np0 + np1 + np2, NP);
  const int4 realStart = make_int4(0, n_gen, n_gen + n_load, n_gen + n_load + n_or);
  const int4 realCnt   = make_int4(n_gen, n_load, n_or, n_ex);

  const int NB = (N + NPB - 1) / NPB;   // buckets (<=256 for N<=131072)

  // ---- workspace layout (row-major bf16 activations) ----
  size_t NPel = (size_t)NP * HD;
  size_t nel  = (size_t)N * HD;
  unsigned short* b0 = (unsigned short*)d_ws;  // h1 (padded) -> later agg buffer
  unsigned short* b1 = b0 + NPel;              // x current
  unsigned short* b3 = b1 + nel;               // x next
  int*  gcnt = (int*)(b3 + nel);               // 256 ints
  int*  ebuf = gcnt + 256;                     // NB*CAP packed edges
  int*  csr  = ebuf + (size_t)NB * CAP;
  int*  offs = csr + (size_t)NB * CAP;
  int*  deg  = offs + N;
  float* inv_deg = (float*)(deg + N);
  float* zl = inv_deg + N;
  float* zr = zl + N;
  int*  invp = (int*)(zr + N);
  uintptr_t wp_addr = ((uintptr_t)(invp + N) + 15) & ~(uintptr_t)15;
  unsigned short* Wp = (unsigned short*)wp_addr;   // 4*16384 + 3*32768 bf16

  // ---- weight repack + invptv + gcnt zero (one launch) ----
  wprep_all_kernel<<<640, 256, 0, stream>>>(Wg2, Wld2, Wor2, Wex2, Wl_h, Wr_h, Wp,
                                            ptv, invp, gcnt, N);

  // ---- embeddings ----
  embed1_kernel<<<NP / 2, 256, 0, stream>>>(x_gen, x_load, x_or, x_ex,
                                            Wg1, bg1, Wld1, bld1, Wor1, bor1, Wex1, bex1,
                                            b0, padCum, realCnt);
  mfma_embed2_kernel<<<NP / 64, 256, 0, stream>>>(b0, Wp, bg2, bld2, bor2, bex2,
                                                  invp, b1, padCum, realStart, realCnt);

  // ---- CSR build (bucketed, LDS-local atomics) ----
  bucket_scatter_kernel<<<(nE + SCHUNK - 1) / SCHUNK, 256, 0, stream>>>(esrc, edst, gcnt, ebuf, nE);
  bucket_build_kernel<<<NB, 256, 0, stream>>>(ebuf, gcnt, csr, offs, deg, inv_deg, N);

  // ---- hidden SAGE layers ----
  const int aggGrid = (N + 15) / 16;
  const unsigned short* WpC = Wp + 4 * 16384;
  unsigned short* xcur = b1;
  unsigned short* xnext = b3;
  for (int l = 0; l < 2; l++) {
    agg_rm_kernel<<<aggGrid, 256, 0, stream>>>(xcur, csr, offs, deg, inv_deg, b0, N);
    mfma_comb_kernel<false><<<(N + 63) / 64, 256, 0, stream>>>(
        b0, xcur, WpC + (size_t)l * 32768, bl_h + (size_t)l * HD, xnext,
        nullptr, nullptr, nullptr, nullptr, N);
    unsigned short* tmp = xcur; xcur = xnext; xnext = tmp;
  }
  // layer 3 fused with output projection (zl = x3.Wl_o, zr = x3.Wr_o)
  agg_rm_kernel<<<aggGrid, 256, 0, stream>>>(xcur, csr, offs, deg, inv_deg, b0, N);
  mfma_comb_kernel<true><<<(N + 63) / 64, 256, 0, stream>>>(
      b0, xcur, WpC + 2 * 32768, bl_h + 2 * HD, nullptr,
      Wl_o, Wr_o, zl, zr, N);

  // ---- final scalar aggregation + sigmoid ----
  zfinal_kernel<<<(N + 255) / 256, 256, 0, stream>>>(zl, zr, csr, offs, deg, inv_deg,
                                                     bl_o, (float*)d_out, N);
}

// Round 7
// 345.221 us; speedup vs baseline: 2.6670x; 1.1675x over previous
//
#include <hip/hip_runtime.h>
#include <hip/hip_bf16.h>
#include <math.h>

#define HD 128
#define NPB 512        // nodes per bucket
#define CAP 16384      // edge capacity per bucket (avg ~8163 -> 2x headroom)
#define SCHUNK 4096    // edges per scatter block
#define ALCSR 768      // staged csr entries per 16-node block (avg ~256)

typedef __attribute__((ext_vector_type(8))) short  bf16x8;
typedef __attribute__((ext_vector_type(4))) float  f32x4;

__device__ __forceinline__ float lrelu(float v) { return v > 0.0f ? v : 0.1f * v; }

__device__ __forceinline__ unsigned short f2bf(float f) {
  union { float f; unsigned u; } c; c.f = f;
  unsigned u = c.u + 0x7fffu + ((c.u >> 16) & 1u);   // RNE
  return (unsigned short)(u >> 16);
}
__device__ __forceinline__ float bf2f(unsigned short u) {
  return __uint_as_float((unsigned)u << 16);
}

// ---------------- embedding layer 1 (all types, padded node ids) ----------------
__global__ __launch_bounds__(256)
void embed1_kernel(const float* __restrict__ xg, const float* __restrict__ xl,
                   const float* __restrict__ xo, const float* __restrict__ xe,
                   const float* __restrict__ Wg, const float* __restrict__ bg,
                   const float* __restrict__ Wl, const float* __restrict__ bl,
                   const float* __restrict__ Wo, const float* __restrict__ bo,
                   const float* __restrict__ We, const float* __restrict__ be,
                   unsigned short* __restrict__ h1, int4 padCum, int4 realCnt) {
  int p = blockIdx.x * 2 + (threadIdx.x >> 7);
  if (p >= padCum.w) return;
  int j = threadIdx.x & 127;
  int typ = (p < padCum.x) ? 0 : (p < padCum.y) ? 1 : (p < padCum.z) ? 2 : 3;
  int padStart = (typ == 0) ? 0 : (typ == 1) ? padCum.x : (typ == 2) ? padCum.y : padCum.z;
  int cnt = (typ == 0) ? realCnt.x : (typ == 1) ? realCnt.y : (typ == 2) ? realCnt.z : realCnt.w;
  int loc = p - padStart;
  if (loc >= cnt) return;
  const float *x, *W, *bb; int IN;
  if (typ == 0)      { x = xg; W = Wg; bb = bg; IN = 3; }
  else if (typ == 1) { x = xl; W = Wl; bb = bl; IN = 3; }
  else if (typ == 2) { x = xo; W = Wo; bb = bo; IN = 6; }
  else               { x = xe; W = We; bb = be; IN = 6; }
  float acc = bb[j];
  for (int k = 0; k < IN; k++) acc += x[(size_t)loc * IN + k] * W[k * HD + j];
  h1[(size_t)p * HD + j] = f2bf(lrelu(acc));
}

// ---------------- weight repack + invptv + gcnt zero ----------------
__global__ __launch_bounds__(256)
void wprep_all_kernel(const float* __restrict__ Wg2, const float* __restrict__ Wld2,
                      const float* __restrict__ Wor2, const float* __restrict__ Wex2,
                      const float* __restrict__ Wl_h, const float* __restrict__ Wr_h,
                      unsigned short* __restrict__ Wp,
                      const int* __restrict__ ptv, int* __restrict__ inv,
                      int* __restrict__ gcnt, int n) {
  int tid = blockIdx.x * 256 + threadIdx.x;      // 10 * 16384 total
  if (tid < 256) gcnt[tid] = 0;
  if (tid < n) inv[ptv[tid]] = tid;
  int m = tid >> 14;
  int i = tid & 16383;
  const float* src; unsigned short* dst;
  switch (m) {
    case 0: src = Wg2;  dst = Wp;             break;
    case 1: src = Wld2; dst = Wp + 16384;     break;
    case 2: src = Wor2; dst = Wp + 2 * 16384; break;
    case 3: src = Wex2; dst = Wp + 3 * 16384; break;
    default: {
      int mm = m - 4; int l = mm >> 1; int isR = mm & 1;
      src = (isR ? Wr_h : Wl_h) + (size_t)l * 16384;
      dst = Wp + 4 * 16384 + (size_t)l * 32768 + (isR ? 16384 : 0);
    }
  }
  int k = i >> 7, j = i & 127;
  int ks = k >> 5, g = (k >> 3) & 3, b = k & 7;
  dst[((ks * 128 + j) * 4 + g) * 8 + b] = f2bf(src[i]);
}

// ---------------- embedding layer 2 (MFMA), row-major out via invp ----------------
__global__ __launch_bounds__(256)
void mfma_embed2_kernel(const unsigned short* __restrict__ h1,
                        const unsigned short* __restrict__ Wp,
                        const float* __restrict__ b_g, const float* __restrict__ b_ld,
                        const float* __restrict__ b_or, const float* __restrict__ b_ex,
                        const int* __restrict__ inv, unsigned short* __restrict__ out,
                        int4 padCum, int4 realStart, int4 realCnt) {
  const int t = threadIdx.x, w = t >> 6, l = t & 63;
  const int lr = l & 15, lg = l >> 4;
  const int prow0 = blockIdx.x * 64 + w * 16;
  int typ = (prow0 < padCum.x) ? 0 : (prow0 < padCum.y) ? 1 : (prow0 < padCum.z) ? 2 : 3;
  int padStart = (typ == 0) ? 0 : (typ == 1) ? padCum.x : (typ == 2) ? padCum.y : padCum.z;
  int rStart = (typ == 0) ? realStart.x : (typ == 1) ? realStart.y : (typ == 2) ? realStart.z : realStart.w;
  int cnt = (typ == 0) ? realCnt.x : (typ == 1) ? realCnt.y : (typ == 2) ? realCnt.z : realCnt.w;
  const float* bias = (typ == 0) ? b_g : (typ == 1) ? b_ld : (typ == 2) ? b_or : b_ex;

  int raLoc = prow0 + lr - padStart; if (raLoc >= cnt) raLoc = cnt - 1;
  const unsigned short* abase = h1 + (size_t)(padStart + raLoc) * HD + 8 * lg;
  const unsigned short* wbase = Wp + (size_t)typ * 16384 + lr * 32 + lg * 8;

  f32x4 acc[8];
  #pragma unroll
  for (int cb = 0; cb < 8; cb++) {
    float bv = bias[cb * 16 + lr];
    acc[cb] = (f32x4){bv, bv, bv, bv};
  }
  #pragma unroll
  for (int ks = 0; ks < 4; ks++) {
    bf16x8 af = *(const bf16x8*)(abase + ks * 32);
    #pragma unroll
    for (int cb = 0; cb < 8; cb++) {
      bf16x8 bfv = *(const bf16x8*)(wbase + (size_t)(ks * 128 + cb * 16) * 32);
      acc[cb] = __builtin_amdgcn_mfma_f32_16x16x32_bf16(af, bfv, acc[cb], 0, 0, 0);
    }
  }
  int tgt[4];
  #pragma unroll
  for (int r = 0; r < 4; r++) {
    int locRow = prow0 + lg * 4 + r - padStart;
    tgt[r] = (locRow < cnt) ? inv[rStart + locRow] : -1;
  }
  #pragma unroll
  for (int cb = 0; cb < 8; cb++) {
    #pragma unroll
    for (int r = 0; r < 4; r++) {
      if (tgt[r] >= 0)
        out[(size_t)tgt[r] * HD + cb * 16 + lr] = f2bf(lrelu(acc[cb][r]));
    }
  }
}

// ---------------- CSR build phase 1: bucket scatter (packed int) ----------------
__global__ __launch_bounds__(256)
void bucket_scatter_kernel(const int* __restrict__ esrc, const int* __restrict__ edst,
                           int* __restrict__ gcnt, int* __restrict__ ebuf, int nE) {
  __shared__ int cnt[256];
  __shared__ int cur[256];
  const int t = threadIdx.x;
  const int c0 = blockIdx.x * SCHUNK;
  int s_arr[16], d_arr[16];
  cnt[t] = 0;
  __syncthreads();
  #pragma unroll
  for (int k = 0; k < 16; k++) {
    int idx = c0 + k * 256 + t;
    if (idx < nE) {
      s_arr[k] = esrc[idx];
      int d = edst[idx];
      d_arr[k] = d;
      atomicAdd(&cnt[d >> 9], 1);
    } else d_arr[k] = -1;
  }
  __syncthreads();
  if (cnt[t] > 0) cur[t] = atomicAdd(&gcnt[t], cnt[t]);
  __syncthreads();
  #pragma unroll
  for (int k = 0; k < 16; k++) {
    if (d_arr[k] >= 0) {
      int b = d_arr[k] >> 9;
      int p = atomicAdd(&cur[b], 1);
      ebuf[(size_t)b * CAP + p] = (s_arr[k] << 9) | (d_arr[k] & 511);
    }
  }
}

__device__ __forceinline__ int wave_incl_scan(int v) {
  int lane = threadIdx.x & 63;
  #pragma unroll
  for (int d = 1; d < 64; d <<= 1) {
    int tv = __shfl_up(v, d, 64);
    if (lane >= d) v += tv;
  }
  return v;
}

// ---------------- CSR build phase 2: per-bucket local build ----------------
__global__ __launch_bounds__(256)
void bucket_build_kernel(const int* __restrict__ ebuf, const int* __restrict__ gcnt,
                         int* __restrict__ csr, int* __restrict__ offs,
                         int* __restrict__ deg, float* __restrict__ inv_deg, int n) {
  __shared__ int hist[512];
  __shared__ int offl[512];
  __shared__ int wsum[4];
  const int b = blockIdx.x, t = threadIdx.x;
  const int cnt = gcnt[b];
  const size_t ebase = (size_t)b * CAP;
  hist[t] = 0; hist[t + 256] = 0;
  __syncthreads();
  for (int i = t; i < cnt; i += 256) {
    int e = ebuf[ebase + i];
    atomicAdd(&hist[e & 511], 1);
  }
  __syncthreads();
  int a0 = hist[2 * t], a1 = hist[2 * t + 1];
  int s = a0 + a1;
  int incl = wave_incl_scan(s);
  int wid = t >> 6;
  if ((t & 63) == 63) wsum[wid] = incl;
  __syncthreads();
  int wbase = 0;
  for (int w_ = 0; w_ < wid; w_++) wbase += wsum[w_];
  int excl = wbase + incl - s;
  offl[2 * t] = excl;
  offl[2 * t + 1] = excl + a0;
  __syncthreads();
  const int d0 = b << 9;
  for (int i = t; i < 512; i += 256) {
    int g = d0 + i;
    if (g < n) {
      offs[g] = b * CAP + offl[i];
      int dg = hist[i];
      deg[g] = dg;
      inv_deg[g] = 1.0f / fmaxf((float)dg, 1.0f);
    }
  }
  __syncthreads();
  for (int i = t; i < cnt; i += 256) {
    int e = ebuf[ebase + i];
    int p = atomicAdd(&offl[e & 511], 1);
    csr[ebase + p] = ((unsigned)e) >> 9;
  }
}

// ---------------- fused SAGE layer: gather-mean + MFMA combine ----------------
// 16 nodes per block. Phase 1: row-major gather (16 lanes x 16B = 4 full 64B
// lines per edge), mean -> LDS (stride 136 shorts, 2-way-only bank alias).
// Phase 2: 4 waves split the 8 col-frags of one 16-row MFMA tile over
// K=256 ([agg | root]); root x read from global. EMIT_Z: project to zl/zr.
template<bool EMIT_Z>
__global__ __launch_bounds__(256)
void sage_fused_kernel(const unsigned short* __restrict__ x, const int* __restrict__ csr,
                       const int* __restrict__ offs, const int* __restrict__ deg,
                       const float* __restrict__ inv_deg,
                       const unsigned short* __restrict__ Wp, const float* __restrict__ bias,
                       unsigned short* __restrict__ out,
                       const float* __restrict__ wl, const float* __restrict__ wr,
                       float* __restrict__ zl, float* __restrict__ zr, int n) {
  __shared__ int lcsr[ALCSR];
  __shared__ __align__(16) unsigned short lagg[16][136];
  __shared__ float zpart[2][4][16];
  const int t = threadIdx.x;
  const int node0 = blockIdx.x * 16;
  int last = node0 + 15; if (last >= n) last = n - 1;
  const int s_begin = offs[node0];
  const int total = offs[last] + deg[last] - s_begin;   // contiguous: 16 | NPB
  const bool useLds = (total <= ALCSR);
  if (useLds) {
    for (int k = t; k < total; k += 256) lcsr[k] = csr[s_begin + k];
  }
  __syncthreads();

  const int w = t >> 6, l = t & 63;
  {  // ---- gather phase ----
    const int g = l >> 4, j = l & 15;
    const int node = node0 + w * 4 + g;
    if (node < n) {
      const unsigned short* xj = x + 8 * j;
      const int lb = offs[node] - s_begin;
      const int d = deg[node];
      float2 a0[4] = {{0.f,0.f},{0.f,0.f},{0.f,0.f},{0.f,0.f}};
      float2 a1[4] = {{0.f,0.f},{0.f,0.f},{0.f,0.f},{0.f,0.f}};
      int i = 0;
      if (useLds) {
        for (; i + 1 < d; i += 2) {
          int e0 = lcsr[lb + i], e1 = lcsr[lb + i + 1];
          uint4 v0 = *(const uint4*)(xj + (size_t)e0 * HD);
          uint4 v1 = *(const uint4*)(xj + (size_t)e1 * HD);
          const unsigned w0[4] = {v0.x, v0.y, v0.z, v0.w};
          const unsigned w1[4] = {v1.x, v1.y, v1.z, v1.w};
          #pragma unroll
          for (int k = 0; k < 4; k++) {
            a0[k] = make_float2(a0[k].x + __uint_as_float(w0[k] << 16),
                                a0[k].y + __uint_as_float(w0[k] & 0xffff0000u));
            a1[k] = make_float2(a1[k].x + __uint_as_float(w1[k] << 16),
                                a1[k].y + __uint_as_float(w1[k] & 0xffff0000u));
          }
        }
        if (i < d) {
          int e0 = lcsr[lb + i];
          uint4 v0 = *(const uint4*)(xj + (size_t)e0 * HD);
          const unsigned w0[4] = {v0.x, v0.y, v0.z, v0.w};
          #pragma unroll
          for (int k = 0; k < 4; k++)
            a0[k] = make_float2(a0[k].x + __uint_as_float(w0[k] << 16),
                                a0[k].y + __uint_as_float(w0[k] & 0xffff0000u));
        }
      } else {
        const int* gcsr = csr + s_begin + lb;
        for (; i + 1 < d; i += 2) {
          int e0 = gcsr[i], e1 = gcsr[i + 1];
          uint4 v0 = *(const uint4*)(xj + (size_t)e0 * HD);
          uint4 v1 = *(const uint4*)(xj + (size_t)e1 * HD);
          const unsigned w0[4] = {v0.x, v0.y, v0.z, v0.w};
          const unsigned w1[4] = {v1.x, v1.y, v1.z, v1.w};
          #pragma unroll
          for (int k = 0; k < 4; k++) {
            a0[k] = make_float2(a0[k].x + __uint_as_float(w0[k] << 16),
                                a0[k].y + __uint_as_float(w0[k] & 0xffff0000u));
            a1[k] = make_float2(a1[k].x + __uint_as_float(w1[k] << 16),
                                a1[k].y + __uint_as_float(w1[k] & 0xffff0000u));
          }
        }
        if (i < d) {
          int e0 = gcsr[i];
          uint4 v0 = *(const uint4*)(xj + (size_t)e0 * HD);
          const unsigned w0[4] = {v0.x, v0.y, v0.z, v0.w};
          #pragma unroll
          for (int k = 0; k < 4; k++)
            a0[k] = make_float2(a0[k].x + __uint_as_float(w0[k] << 16),
                                a0[k].y + __uint_as_float(w0[k] & 0xffff0000u));
        }
      }
      const float id = inv_deg[node];
      uint4 o;
      unsigned* op = (unsigned*)&o;
      #pragma unroll
      for (int k = 0; k < 4; k++) {
        float lo = (a0[k].x + a1[k].x) * id;
        float hi = (a0[k].y + a1[k].y) * id;
        op[k] = (unsigned)f2bf(lo) | ((unsigned)f2bf(hi) << 16);
      }
      *(uint4*)&lagg[w * 4 + g][j * 8] = o;
    }
  }
  __syncthreads();

  // ---- MFMA phase: wave w owns col-frags 2w, 2w+1 ----
  const int lr = l & 15, lg = l >> 4;
  int ra = node0 + lr; if (ra >= n) ra = n - 1;
  const unsigned short* wbase = Wp + (size_t)lr * 32 + (size_t)lg * 8;
  const unsigned short* rbase = x + (size_t)ra * HD + 8 * lg;

  f32x4 acc[2];
  #pragma unroll
  for (int c = 0; c < 2; c++) {
    float bv = bias[(2 * w + c) * 16 + lr];
    acc[c] = (f32x4){bv, bv, bv, bv};
  }
  #pragma unroll
  for (int ks = 0; ks < 4; ks++) {
    bf16x8 af = *(const bf16x8*)&lagg[lr][lg * 8 + ks * 32];
    #pragma unroll
    for (int c = 0; c < 2; c++) {
      int cb = 2 * w + c;
      bf16x8 bfv = *(const bf16x8*)(wbase + (size_t)(ks * 128 + cb * 16) * 32);
      acc[c] = __builtin_amdgcn_mfma_f32_16x16x32_bf16(af, bfv, acc[c], 0, 0, 0);
    }
  }
  #pragma unroll
  for (int ks = 0; ks < 4; ks++) {
    bf16x8 af = *(const bf16x8*)(rbase + ks * 32);
    #pragma unroll
    for (int c = 0; c < 2; c++) {
      int cb = 2 * w + c;
      bf16x8 bfv = *(const bf16x8*)(wbase + (size_t)((4 + ks) * 128 + cb * 16) * 32);
      acc[c] = __builtin_amdgcn_mfma_f32_16x16x32_bf16(af, bfv, acc[c], 0, 0, 0);
    }
  }

  if constexpr (!EMIT_Z) {
    #pragma unroll
    for (int c = 0; c < 2; c++) {
      int cb = 2 * w + c;
      #pragma unroll
      for (int r = 0; r < 4; r++) {
        int node = node0 + lg * 4 + r;
        if (node < n)
          out[(size_t)node * HD + cb * 16 + lr] = f2bf(lrelu(acc[c][r]));
      }
    }
  } else {
    float vl[4] = {0.f, 0.f, 0.f, 0.f}, vr[4] = {0.f, 0.f, 0.f, 0.f};
    #pragma unroll
    for (int c = 0; c < 2; c++) {
      int cb = 2 * w + c;
      float wlv = wl[cb * 16 + lr];
      float wrv = wr[cb * 16 + lr];
      #pragma unroll
      for (int r = 0; r < 4; r++) {
        float x3 = lrelu(acc[c][r]);
        vl[r] += x3 * wlv;
        vr[r] += x3 * wrv;
      }
    }
    #pragma unroll
    for (int r = 0; r < 4; r++) {
      #pragma unroll
      for (int d = 1; d < 16; d <<= 1) {
        vl[r] += __shfl_xor(vl[r], d, 64);
        vr[r] += __shfl_xor(vr[r], d, 64);
      }
    }
    if (lr == 0) {
      #pragma unroll
      for (int r = 0; r < 4; r++) {
        zpart[0][w][lg * 4 + r] = vl[r];
        zpart[1][w][lg * 4 + r] = vr[r];
      }
    }
    __syncthreads();
    if (t < 16) {
      int node = node0 + t;
      if (node < n) {
        zl[node] = zpart[0][0][t] + zpart[0][1][t] + zpart[0][2][t] + zpart[0][3][t];
        zr[node] = zpart[1][0][t] + zpart[1][1][t] + zpart[1][2][t] + zpart[1][3][t];
      }
    }
  }
}

// ---------------- final: out = sigmoid(mean(zl) + zr + bl) ----------------
__global__ __launch_bounds__(256)
void zfinal_kernel(const float* __restrict__ zl, const float* __restrict__ zr,
                   const int* __restrict__ csr, const int* __restrict__ offs,
                   const int* __restrict__ deg, const float* __restrict__ inv_deg,
                   const float* __restrict__ bl, float* __restrict__ out, int n) {
  int i = blockIdx.x * 256 + threadIdx.x;
  if (i >= n) return;
  int s0 = offs[i], d = deg[i];
  float a = 0.f;
  #pragma unroll 4
  for (int e = 0; e < d; e++) a += zl[csr[s0 + e]];
  float s = a * inv_deg[i] + bl[0] + zr[i];
  out[i] = 1.0f / (1.0f + expf(-s));
}

extern "C" void kernel_launch(void* const* d_in, const int* in_sizes, int n_in,
                              void* d_out, int out_size, void* d_ws, size_t ws_size,
                              hipStream_t stream) {
  const float* x_gen  = (const float*)d_in[0];
  const float* x_load = (const float*)d_in[1];
  const float* x_or   = (const float*)d_in[2];
  const float* x_ex   = (const float*)d_in[3];
  const int*   edge   = (const int*)d_in[4];
  const int*   ptv    = (const int*)d_in[5];
  const float* Wg1  = (const float*)d_in[6],  *bg1  = (const float*)d_in[7];
  const float* Wg2  = (const float*)d_in[8],  *bg2  = (const float*)d_in[9];
  const float* Wld1 = (const float*)d_in[10], *bld1 = (const float*)d_in[11];
  const float* Wld2 = (const float*)d_in[12], *bld2 = (const float*)d_in[13];
  const float* Wor1 = (const float*)d_in[14], *bor1 = (const float*)d_in[15];
  const float* Wor2 = (const float*)d_in[16], *bor2 = (const float*)d_in[17];
  const float* Wex1 = (const float*)d_in[18], *bex1 = (const float*)d_in[19];
  const float* Wex2 = (const float*)d_in[20], *bex2 = (const float*)d_in[21];
  const float* Wl_h = (const float*)d_in[22], *bl_h = (const float*)d_in[23];
  const float* Wr_h = (const float*)d_in[24];
  const float* Wl_o = (const float*)d_in[25], *bl_o = (const float*)d_in[26];
  const float* Wr_o = (const float*)d_in[27];

  const int n_gen  = in_sizes[0] / 3;
  const int n_load = in_sizes[1] / 3;
  const int n_or   = in_sizes[2] / 6;
  const int n_ex   = in_sizes[3] / 6;
  const int nE     = in_sizes[4] / 2;
  const int N      = in_sizes[5];
  const int* esrc = edge;
  const int* edst = edge + nE;

  // padded segment geometry (each segment rounded to 64 rows)
  const int np0 = ((n_gen  + 63) / 64) * 64;
  const int np1 = ((n_load + 63) / 64) * 64;
  const int np2 = ((n_or   + 63) / 64) * 64;
  const int np3 = ((n_ex   + 63) / 64) * 64;
  const int NP  = np0 + np1 + np2 + np3;
  const int4 padCum    = make_int4(np0, np0 + np1, np0 + np1 + np2, NP);
  const int4 realStart = make_int4(0, n_gen, n_gen + n_load, n_gen + n_load + n_or);
  const int4 realCnt   = make_int4(n_gen, n_load, n_or, n_ex);

  const int NB = (N + NPB - 1) / NPB;   // buckets (<=256 for N<=131072)

  // ---- workspace layout (row-major bf16 activations) ----
  size_t NPel = (size_t)NP * HD;
  size_t nel  = (size_t)N * HD;
  unsigned short* b0 = (unsigned short*)d_ws;  // h1 (padded)
  unsigned short* b1 = b0 + NPel;              // x current
  unsigned short* b3 = b1 + nel;               // x next
  int*  gcnt = (int*)(b3 + nel);               // 256 ints
  int*  ebuf = gcnt + 256;                     // NB*CAP packed edges
  int*  csr  = ebuf + (size_t)NB * CAP;
  int*  offs = csr + (size_t)NB * CAP;
  int*  deg  = offs + N;
  float* inv_deg = (float*)(deg + N);
  float* zl = inv_deg + N;
  float* zr = zl + N;
  int*  invp = (int*)(zr + N);
  uintptr_t wp_addr = ((uintptr_t)(invp + N) + 15) & ~(uintptr_t)15;
  unsigned short* Wp = (unsigned short*)wp_addr;   // 4*16384 + 3*32768 bf16

  // ---- weight repack + invptv + gcnt zero (one launch) ----
  wprep_all_kernel<<<640, 256, 0, stream>>>(Wg2, Wld2, Wor2, Wex2, Wl_h, Wr_h, Wp,
                                            ptv, invp, gcnt, N);

  // ---- embeddings ----
  embed1_kernel<<<NP / 2, 256, 0, stream>>>(x_gen, x_load, x_or, x_ex,
                                            Wg1, bg1, Wld1, bld1, Wor1, bor1, Wex1, bex1,
                                            b0, padCum, realCnt);
  mfma_embed2_kernel<<<NP / 64, 256, 0, stream>>>(b0, Wp, bg2, bld2, bor2, bex2,
                                                  invp, b1, padCum, realStart, realCnt);

  // ---- CSR build (bucketed, LDS-local atomics) ----
  bucket_scatter_kernel<<<(nE + SCHUNK - 1) / SCHUNK, 256, 0, stream>>>(esrc, edst, gcnt, ebuf, nE);
  bucket_build_kernel<<<NB, 256, 0, stream>>>(ebuf, gcnt, csr, offs, deg, inv_deg, N);

  // ---- hidden SAGE layers (fused gather+combine) ----
  const int fGrid = (N + 15) / 16;
  const unsigned short* WpC = Wp + 4 * 16384;
  unsigned short* xcur = b1;
  unsigned short* xnext = b3;
  for (int l = 0; l < 2; l++) {
    sage_fused_kernel<false><<<fGrid, 256, 0, stream>>>(
        xcur, csr, offs, deg, inv_deg, WpC + (size_t)l * 32768,
        bl_h + (size_t)l * HD, xnext, nullptr, nullptr, nullptr, nullptr, N);
    unsigned short* tmp = xcur; xcur = xnext; xnext = tmp;
  }
  // layer 3 fused with output projection (zl = x3.Wl_o, zr = x3.Wr_o)
  sage_fused_kernel<true><<<fGrid, 256, 0, stream>>>(
      xcur, csr, offs, deg, inv_deg, WpC + 2 * 32768,
      bl_h + 2 * HD, nullptr, Wl_o, Wr_o, zl, zr, N);

  // ---- final scalar aggregation + sigmoid ----
  zfinal_kernel<<<(N + 255) / 256, 256, 0, stream>>>(zl, zr, csr, offs, deg, inv_deg,
                                                     bl_o, (float*)d_out, N);
}